// Round 1
// baseline (5528.193 us; speedup 1.0000x reference)
//
#include <hip/hip_runtime.h>
#include <math.h>

#define N_NODES 50000
#define IN_CH   512
#define HID     8
#define HEADS   8
#define C1      64      // HEADS*HID
#define OUT_CH  40
#define NEG_SLOPE 0.2f

__device__ __forceinline__ float leaky(float v) { return v > 0.f ? v : NEG_SLOPE * v; }

// ---------------------------------------------------------------------------
// K1: fused  h1 = (x @ W1) / rowsum(x);  a_src/a_dst per (node,head);
//     self-loop init of out1acc / denom1.
// block = 256 (4 waves), 16 rows per block, each wave handles 4 rows.
// ---------------------------------------------------------------------------
__global__ __launch_bounds__(256) void k_gemm1(
    const float* __restrict__ x, const float* __restrict__ W1,
    const float* __restrict__ attS, const float* __restrict__ attD,
    float* __restrict__ h1, float* __restrict__ out1acc,
    float* __restrict__ denom1, float* __restrict__ aS, float* __restrict__ aD)
{
    __shared__ float xs[16][IN_CH];
    const int tid = threadIdx.x;
    const int j   = tid & 63;     // output column 0..63
    const int w   = tid >> 6;     // wave id 0..3
    const int rowBase = blockIdx.x * 16;

    // stage 16 rows of x (16*512 floats) coalesced as float4
    {
        const float4* xg  = (const float4*)(x + (size_t)rowBase * IN_CH);
        float4*       xls = (float4*)(&xs[0][0]);
        #pragma unroll
        for (int i = 0; i < 8; ++i)
            xls[tid + i * 256] = xg[tid + i * 256];
    }
    __syncthreads();

    const int r0 = w * 4;         // this wave's first row slot

    // row sums (lane-parallel + butterfly)
    float rs[4];
    #pragma unroll
    for (int m = 0; m < 4; ++m) {
        const float4* p = (const float4*)(&xs[r0 + m][j * 8]);
        float4 a = p[0], b = p[1];
        float s = a.x + a.y + a.z + a.w + b.x + b.y + b.z + b.w;
        #pragma unroll
        for (int off = 32; off; off >>= 1) s += __shfl_xor(s, off, 64);
        rs[m] = fmaxf(s, 1e-8f);
    }

    float acc0 = 0.f, acc1 = 0.f, acc2 = 0.f, acc3 = 0.f;
    #pragma unroll 4
    for (int k4 = 0; k4 < IN_CH / 4; ++k4) {
        const int k = k4 * 4;
        const float w0 = W1[(k + 0) * 64 + j];
        const float w1_ = W1[(k + 1) * 64 + j];
        const float w2_ = W1[(k + 2) * 64 + j];
        const float w3_ = W1[(k + 3) * 64 + j];
        float4 v;
        v = *(const float4*)(&xs[r0 + 0][k]);
        acc0 = fmaf(v.x, w0, fmaf(v.y, w1_, fmaf(v.z, w2_, fmaf(v.w, w3_, acc0))));
        v = *(const float4*)(&xs[r0 + 1][k]);
        acc1 = fmaf(v.x, w0, fmaf(v.y, w1_, fmaf(v.z, w2_, fmaf(v.w, w3_, acc1))));
        v = *(const float4*)(&xs[r0 + 2][k]);
        acc2 = fmaf(v.x, w0, fmaf(v.y, w1_, fmaf(v.z, w2_, fmaf(v.w, w3_, acc2))));
        v = *(const float4*)(&xs[r0 + 3][k]);
        acc3 = fmaf(v.x, w0, fmaf(v.y, w1_, fmaf(v.z, w2_, fmaf(v.w, w3_, acc3))));
    }

    const float attSj = attS[j];
    const float attDj = attD[j];
    float accs[4] = {acc0, acc1, acc2, acc3};

    #pragma unroll
    for (int m = 0; m < 4; ++m) {
        const int row = rowBase + r0 + m;
        const float val = accs[m] / rs[m];
        float vs = val * attSj;
        float vd = val * attDj;
        // reduce within 8-lane head group; butterfly -> all 8 lanes hold the sum
        #pragma unroll
        for (int off = 4; off; off >>= 1) {
            vs += __shfl_xor(vs, off, 64);
            vd += __shfl_xor(vd, off, 64);
        }
        const float e = expf(leaky(vs + vd));   // self-loop edge weight
        h1[(size_t)row * 64 + j]      = val;
        out1acc[(size_t)row * 64 + j] = e * val;
        if ((j & 7) == 0) {
            const int hh = j >> 3;
            denom1[(size_t)row * 8 + hh] = e;
            aS[(size_t)row * 8 + hh]     = vs;
            aD[(size_t)row * 8 + hh]     = vd;
        }
    }
}

// ---------------------------------------------------------------------------
// K2: edge pass layer 1. thread = (edge, head). 8 msg atomics + 1 denom atomic.
// ---------------------------------------------------------------------------
__global__ __launch_bounds__(256) void k_edge1(
    const int* __restrict__ src, const int* __restrict__ dst, int E,
    const float* __restrict__ aS, const float* __restrict__ aD,
    const float* __restrict__ h1,
    float* __restrict__ out1acc, float* __restrict__ denom1)
{
    const int idx = blockIdx.x * 256 + threadIdx.x;
    if (idx >= E * 8) return;
    const int e = idx >> 3;
    const int h = idx & 7;
    const int s = src[e];
    const int d = dst[e];
    const float a  = aS[(size_t)s * 8 + h] + aD[(size_t)d * 8 + h];
    const float ee = expf(leaky(a));
    atomicAdd(&denom1[(size_t)d * 8 + h], ee);
    const float4* hp = (const float4*)(h1 + (size_t)s * 64 + h * 8);
    const float4 m0 = hp[0];
    const float4 m1 = hp[1];
    float* o = out1acc + (size_t)d * 64 + h * 8;
    atomicAdd(o + 0, ee * m0.x);
    atomicAdd(o + 1, ee * m0.y);
    atomicAdd(o + 2, ee * m0.z);
    atomicAdd(o + 3, ee * m0.w);
    atomicAdd(o + 4, ee * m1.x);
    atomicAdd(o + 5, ee * m1.y);
    atomicAdd(o + 6, ee * m1.z);
    atomicAdd(o + 7, ee * m1.w);
}

// ---------------------------------------------------------------------------
// K3: finalize layer 1: divide by denom, +b1, ELU (in place -> h_elu)
// ---------------------------------------------------------------------------
__global__ __launch_bounds__(256) void k_fin1(
    float* __restrict__ acc, const float* __restrict__ denom1,
    const float* __restrict__ b1)
{
    const int idx = blockIdx.x * 256 + threadIdx.x;
    if (idx >= N_NODES * 64) return;
    const int row = idx >> 6;
    const int j   = idx & 63;
    float v = acc[idx] / (denom1[(size_t)row * 8 + (j >> 3)] + 1e-16f) + b1[j];
    acc[idx] = v > 0.f ? v : expm1f(v);
}

// ---------------------------------------------------------------------------
// K4: h2 = h_elu @ W2 (64x40); a2 logits; self-loop init of d_out / denom2
// block = 256, 4 rows per block (one per wave)
// ---------------------------------------------------------------------------
__global__ __launch_bounds__(256) void k_gemm2(
    const float* __restrict__ helu, const float* __restrict__ W2,
    const float* __restrict__ attS2, const float* __restrict__ attD2,
    float* __restrict__ h2, float* __restrict__ outacc,
    float* __restrict__ denom2, float* __restrict__ a2s, float* __restrict__ a2d)
{
    __shared__ float w2s[64 * 40];
    __shared__ float xs[4][64];
    const int tid = threadIdx.x;
    for (int i = tid; i < 64 * 40; i += 256) w2s[i] = W2[i];
    const int rowBase = blockIdx.x * 4;
    xs[tid >> 6][tid & 63] = helu[(size_t)rowBase * 64 + tid];
    __syncthreads();

    const int w = tid >> 6;
    const int j = tid & 63;
    const int row = rowBase + w;

    float acc = 0.f;
    if (j < 40) {
        #pragma unroll
        for (int k = 0; k < 64; ++k)
            acc = fmaf(xs[w][k], w2s[k * 40 + j], acc);
    }
    float vs = (j < OUT_CH) ? acc * attS2[j] : 0.f;
    float vd = (j < OUT_CH) ? acc * attD2[j] : 0.f;
    #pragma unroll
    for (int off = 32; off; off >>= 1) {
        vs += __shfl_xor(vs, off, 64);
        vd += __shfl_xor(vd, off, 64);
    }
    const float e = expf(leaky(vs + vd));   // self loop
    if (j < OUT_CH) {
        h2[(size_t)row * 40 + j]     = acc;
        outacc[(size_t)row * 40 + j] = e * acc;
    }
    if (j == 0) {
        denom2[row] = e;
        a2s[row] = vs;
        a2d[row] = vd;
    }
}

// ---------------------------------------------------------------------------
// K5: edge pass layer 2. thread = (edge, quarter): 10 channels each.
// ---------------------------------------------------------------------------
__global__ __launch_bounds__(256) void k_edge2(
    const int* __restrict__ src, const int* __restrict__ dst, int E,
    const float* __restrict__ a2s, const float* __restrict__ a2d,
    const float* __restrict__ h2,
    float* __restrict__ outacc, float* __restrict__ denom2)
{
    const int idx = blockIdx.x * 256 + threadIdx.x;
    if (idx >= E * 4) return;
    const int e = idx >> 2;
    const int q = idx & 3;
    const int s = src[e];
    const int d = dst[e];
    const float ee = expf(leaky(a2s[s] + a2d[d]));
    if (q == 0) atomicAdd(&denom2[d], ee);
    const float2* hp = (const float2*)(h2 + (size_t)s * 40 + q * 10);
    float* o = outacc + (size_t)d * 40 + q * 10;
    #pragma unroll
    for (int i = 0; i < 5; ++i) {
        const float2 m = hp[i];
        atomicAdd(o + 2 * i,     ee * m.x);
        atomicAdd(o + 2 * i + 1, ee * m.y);
    }
}

// ---------------------------------------------------------------------------
// K6: finalize output: divide by denom2, + b2
// ---------------------------------------------------------------------------
__global__ __launch_bounds__(256) void k_fin2(
    float* __restrict__ out, const float* __restrict__ denom2,
    const float* __restrict__ b2)
{
    const int idx = blockIdx.x * 256 + threadIdx.x;
    if (idx >= N_NODES * OUT_CH) return;
    const int row = idx / OUT_CH;
    const int c   = idx - row * OUT_CH;
    out[idx] = out[idx] / (denom2[row] + 1e-16f) + b2[c];
}

// ---------------------------------------------------------------------------
extern "C" void kernel_launch(void* const* d_in, const int* in_sizes, int n_in,
                              void* d_out, int out_size, void* d_ws, size_t ws_size,
                              hipStream_t stream)
{
    const float* x     = (const float*)d_in[0];
    const int*   ei    = (const int*)d_in[1];
    const float* W1    = (const float*)d_in[2];
    const float* attS1 = (const float*)d_in[3];
    const float* attD1 = (const float*)d_in[4];
    const float* b1    = (const float*)d_in[5];
    const float* W2    = (const float*)d_in[6];
    const float* attS2 = (const float*)d_in[7];
    const float* attD2 = (const float*)d_in[8];
    const float* b2    = (const float*)d_in[9];

    const int E = in_sizes[1] / 2;
    const int* src = ei;
    const int* dst = ei + E;

    float* out = (float*)d_out;
    float* f = (float*)d_ws;
    float* h1      = f;                 f += (size_t)N_NODES * 64;
    float* aS1     = f;                 f += (size_t)N_NODES * 8;
    float* aD1     = f;                 f += (size_t)N_NODES * 8;
    float* out1acc = f;                 f += (size_t)N_NODES * 64;
    float* denom1  = f;                 f += (size_t)N_NODES * 8;
    float* h2      = f;                 f += (size_t)N_NODES * 40;
    float* a2s     = f;                 f += (size_t)N_NODES;
    float* a2d     = f;                 f += (size_t)N_NODES;
    float* denom2  = f;                 f += (size_t)N_NODES;

    // Layer 1
    k_gemm1<<<N_NODES / 16, 256, 0, stream>>>(x, W1, attS1, attD1,
                                              h1, out1acc, denom1, aS1, aD1);
    k_edge1<<<(E * 8 + 255) / 256, 256, 0, stream>>>(src, dst, E, aS1, aD1,
                                                     h1, out1acc, denom1);
    k_fin1<<<(N_NODES * 64) / 256, 256, 0, stream>>>(out1acc, denom1, b1);

    // Layer 2
    k_gemm2<<<N_NODES / 4, 256, 0, stream>>>(out1acc, W2, attS2, attD2,
                                             h2, out, denom2, a2s, a2d);
    k_edge2<<<(E * 4 + 255) / 256, 256, 0, stream>>>(src, dst, E, a2s, a2d,
                                                     h2, out, denom2);
    k_fin2<<<(N_NODES * OUT_CH + 255) / 256, 256, 0, stream>>>(out, denom2, b2);
}

// Round 2
// 604.816 us; speedup vs baseline: 9.1403x; 9.1403x over previous
//
#include <hip/hip_runtime.h>
#include <math.h>

#define N_NODES 50000
#define IN_CH   512
#define HID     8
#define HEADS   8
#define C1      64      // HEADS*HID
#define OUT_CH  40
#define NEG_SLOPE 0.2f

__device__ __forceinline__ float leaky(float v) { return v > 0.f ? v : NEG_SLOPE * v; }

// ---------------------------------------------------------------------------
// K1: fused  h1 = (x @ W1) / rowsum(x);  per-(node,head) logits aS/aD.
// block = 256 (4 waves), 16 rows per block, each wave handles 4 rows.
// ---------------------------------------------------------------------------
__global__ __launch_bounds__(256) void k_gemm1(
    const float* __restrict__ x, const float* __restrict__ W1,
    const float* __restrict__ attS, const float* __restrict__ attD,
    float* __restrict__ h1, float* __restrict__ aS, float* __restrict__ aD)
{
    __shared__ float xs[16][IN_CH];
    const int tid = threadIdx.x;
    const int j   = tid & 63;     // output column 0..63
    const int w   = tid >> 6;     // wave id 0..3
    const int rowBase = blockIdx.x * 16;

    // stage 16 rows of x (16*512 floats) coalesced as float4
    {
        const float4* xg  = (const float4*)(x + (size_t)rowBase * IN_CH);
        float4*       xls = (float4*)(&xs[0][0]);
        #pragma unroll
        for (int i = 0; i < 8; ++i)
            xls[tid + i * 256] = xg[tid + i * 256];
    }
    __syncthreads();

    const int r0 = w * 4;         // this wave's first row slot

    // row sums (lane-parallel + butterfly)
    float rs[4];
    #pragma unroll
    for (int m = 0; m < 4; ++m) {
        const float4* p = (const float4*)(&xs[r0 + m][j * 8]);
        float4 a = p[0], b = p[1];
        float s = a.x + a.y + a.z + a.w + b.x + b.y + b.z + b.w;
        #pragma unroll
        for (int off = 32; off; off >>= 1) s += __shfl_xor(s, off, 64);
        rs[m] = fmaxf(s, 1e-8f);
    }

    float acc0 = 0.f, acc1 = 0.f, acc2 = 0.f, acc3 = 0.f;
    #pragma unroll 4
    for (int k4 = 0; k4 < IN_CH / 4; ++k4) {
        const int k = k4 * 4;
        const float w0  = W1[(k + 0) * 64 + j];
        const float w1_ = W1[(k + 1) * 64 + j];
        const float w2_ = W1[(k + 2) * 64 + j];
        const float w3_ = W1[(k + 3) * 64 + j];
        float4 v;
        v = *(const float4*)(&xs[r0 + 0][k]);
        acc0 = fmaf(v.x, w0, fmaf(v.y, w1_, fmaf(v.z, w2_, fmaf(v.w, w3_, acc0))));
        v = *(const float4*)(&xs[r0 + 1][k]);
        acc1 = fmaf(v.x, w0, fmaf(v.y, w1_, fmaf(v.z, w2_, fmaf(v.w, w3_, acc1))));
        v = *(const float4*)(&xs[r0 + 2][k]);
        acc2 = fmaf(v.x, w0, fmaf(v.y, w1_, fmaf(v.z, w2_, fmaf(v.w, w3_, acc2))));
        v = *(const float4*)(&xs[r0 + 3][k]);
        acc3 = fmaf(v.x, w0, fmaf(v.y, w1_, fmaf(v.z, w2_, fmaf(v.w, w3_, acc3))));
    }

    const float attSj = attS[j];
    const float attDj = attD[j];
    float accs[4] = {acc0, acc1, acc2, acc3};

    #pragma unroll
    for (int m = 0; m < 4; ++m) {
        const int row = rowBase + r0 + m;
        const float val = accs[m] / rs[m];
        float vs = val * attSj;
        float vd = val * attDj;
        // reduce within 8-lane head group; butterfly -> all 8 lanes hold the sum
        #pragma unroll
        for (int off = 4; off; off >>= 1) {
            vs += __shfl_xor(vs, off, 64);
            vd += __shfl_xor(vd, off, 64);
        }
        h1[(size_t)row * 64 + j] = val;
        if ((j & 7) == 0) {
            const int hh = j >> 3;
            aS[(size_t)row * 8 + hh] = vs;
            aD[(size_t)row * 8 + hh] = vd;
        }
    }
}

// ---------------------------------------------------------------------------
// CSR build: count -> 2-level scan -> scatter (src ids bucketed by dst)
// ---------------------------------------------------------------------------
__global__ __launch_bounds__(256) void k_count(
    const int* __restrict__ dst, int E, int* __restrict__ deg)
{
    const int i = blockIdx.x * 256 + threadIdx.x;
    if (i < E) atomicAdd(&deg[dst[i]], 1);
}

__global__ __launch_bounds__(256) void k_scan_block(
    const int* __restrict__ deg, int* __restrict__ scanned,
    int* __restrict__ partials, int n)
{
    __shared__ int tmp[256];
    const int t = threadIdx.x;
    const int idx = blockIdx.x * 256 + t;
    tmp[t] = (idx < n) ? deg[idx] : 0;
    __syncthreads();
    #pragma unroll
    for (int off = 1; off < 256; off <<= 1) {
        int xv = (t >= off) ? tmp[t - off] : 0;
        __syncthreads();
        tmp[t] += xv;
        __syncthreads();
    }
    if (idx < n) scanned[idx] = tmp[t];
    if (t == 255) partials[blockIdx.x] = tmp[255];
}

__global__ __launch_bounds__(256) void k_scan_partials(
    int* __restrict__ partials, int n)
{
    __shared__ int tmp[256];
    const int t = threadIdx.x;
    tmp[t] = (t < n) ? partials[t] : 0;
    __syncthreads();
    #pragma unroll
    for (int off = 1; off < 256; off <<= 1) {
        int xv = (t >= off) ? tmp[t - off] : 0;
        __syncthreads();
        tmp[t] += xv;
        __syncthreads();
    }
    if (t < n) partials[t] = tmp[t];
}

__global__ __launch_bounds__(256) void k_scan_add(
    const int* __restrict__ scanned, const int* __restrict__ partials,
    const int* __restrict__ deg, int* __restrict__ cum,
    int* __restrict__ cursor, int n)
{
    const int idx = blockIdx.x * 256 + threadIdx.x;
    if (idx >= n) return;
    const int base = blockIdx.x ? partials[blockIdx.x - 1] : 0;
    const int inc = scanned[idx] + base;
    cum[idx] = inc;               // inclusive cumulative degree
    cursor[idx] = inc - deg[idx]; // exclusive start, doubles as scatter cursor
}

__global__ __launch_bounds__(256) void k_scatter(
    const int* __restrict__ src, const int* __restrict__ dst, int E,
    int* __restrict__ cursor, int* __restrict__ ssrc)
{
    const int i = blockIdx.x * 256 + threadIdx.x;
    if (i >= E) return;
    const int pos = atomicAdd(&cursor[dst[i]], 1);
    ssrc[pos] = src[i];
}

// ---------------------------------------------------------------------------
// K-AGG1: one wave per dst node. Gather edges, softmax-aggregate, finalize
// (divide + bias + ELU) -> helu. No atomics.
// ---------------------------------------------------------------------------
__global__ __launch_bounds__(256) void k_agg1(
    const int* __restrict__ cum, const int* __restrict__ ssrc,
    const float* __restrict__ aS, const float* __restrict__ aD,
    const float* __restrict__ h1, const float* __restrict__ b1,
    float* __restrict__ helu)
{
    const int tid  = threadIdx.x;
    const int lane = tid & 63;
    const int node = blockIdx.x * 4 + (tid >> 6);
    if (node >= N_NODES) return;
    const int h = lane >> 3;

    const int start = node ? cum[node - 1] : 0;
    const int end   = cum[node];

    const float aDd = aD[(size_t)node * 8 + h];
    // self loop
    const float e0 = expf(leaky(aS[(size_t)node * 8 + h] + aDd));
    float acc = e0 * h1[(size_t)node * 64 + lane];
    float den = e0;

    for (int base = start; base < end; base += 64) {
        const int nb = min(64, end - base);
        const int sl = (base + lane < end) ? ssrc[base + lane] : 0;
        for (int k = 0; k < nb; ++k) {
            const int s = __shfl(sl, k, 64);
            const float ee = expf(leaky(aS[(size_t)s * 8 + h] + aDd));
            acc += ee * h1[(size_t)s * 64 + lane];
            den += ee;
        }
    }

    const float v = acc / (den + 1e-16f) + b1[lane];
    helu[(size_t)node * 64 + lane] = v > 0.f ? v : expm1f(v);
}

// ---------------------------------------------------------------------------
// K4: h2 = helu @ W2 (64x40); layer-2 logits a2s/a2d.
// block = 256, 4 rows per block (one per wave)
// ---------------------------------------------------------------------------
__global__ __launch_bounds__(256) void k_gemm2(
    const float* __restrict__ helu, const float* __restrict__ W2,
    const float* __restrict__ attS2, const float* __restrict__ attD2,
    float* __restrict__ h2, float* __restrict__ a2s, float* __restrict__ a2d)
{
    __shared__ float w2s[64 * 40];
    __shared__ float xs[4][64];
    const int tid = threadIdx.x;
    for (int i = tid; i < 64 * 40; i += 256) w2s[i] = W2[i];
    const int rowBase = blockIdx.x * 4;
    xs[tid >> 6][tid & 63] = helu[(size_t)rowBase * 64 + tid];
    __syncthreads();

    const int w = tid >> 6;
    const int j = tid & 63;
    const int row = rowBase + w;

    float acc = 0.f;
    if (j < OUT_CH) {
        #pragma unroll
        for (int k = 0; k < 64; ++k)
            acc = fmaf(xs[w][k], w2s[k * 40 + j], acc);
    }
    float vs = (j < OUT_CH) ? acc * attS2[j] : 0.f;
    float vd = (j < OUT_CH) ? acc * attD2[j] : 0.f;
    #pragma unroll
    for (int off = 32; off; off >>= 1) {
        vs += __shfl_xor(vs, off, 64);
        vd += __shfl_xor(vd, off, 64);
    }
    if (j < OUT_CH) h2[(size_t)row * 40 + j] = acc;
    if (j == 0) {
        a2s[row] = vs;
        a2d[row] = vd;
    }
}

// ---------------------------------------------------------------------------
// K-AGG2: one wave per dst node, lanes 0..39 = channels. Finalize + b2 -> out.
// ---------------------------------------------------------------------------
__global__ __launch_bounds__(256) void k_agg2(
    const int* __restrict__ cum, const int* __restrict__ ssrc,
    const float* __restrict__ a2s, const float* __restrict__ a2d,
    const float* __restrict__ h2, const float* __restrict__ b2,
    float* __restrict__ out)
{
    const int tid  = threadIdx.x;
    const int lane = tid & 63;
    const int node = blockIdx.x * 4 + (tid >> 6);
    if (node >= N_NODES) return;

    const int start = node ? cum[node - 1] : 0;
    const int end   = cum[node];

    const float aDd = a2d[node];
    const float e0 = expf(leaky(a2s[node] + aDd));
    float acc = (lane < OUT_CH) ? e0 * h2[(size_t)node * 40 + lane] : 0.f;
    float den = e0;

    for (int base = start; base < end; base += 64) {
        const int nb = min(64, end - base);
        const int sl = (base + lane < end) ? ssrc[base + lane] : 0;
        for (int k = 0; k < nb; ++k) {
            const int s = __shfl(sl, k, 64);
            const float ee = expf(leaky(a2s[s] + aDd));
            if (lane < OUT_CH) acc += ee * h2[(size_t)s * 40 + lane];
            den += ee;
        }
    }

    if (lane < OUT_CH)
        out[(size_t)node * OUT_CH + lane] = acc / (den + 1e-16f) + b2[lane];
}

// ---------------------------------------------------------------------------
extern "C" void kernel_launch(void* const* d_in, const int* in_sizes, int n_in,
                              void* d_out, int out_size, void* d_ws, size_t ws_size,
                              hipStream_t stream)
{
    const float* x     = (const float*)d_in[0];
    const int*   ei    = (const int*)d_in[1];
    const float* W1    = (const float*)d_in[2];
    const float* attS1 = (const float*)d_in[3];
    const float* attD1 = (const float*)d_in[4];
    const float* b1    = (const float*)d_in[5];
    const float* W2    = (const float*)d_in[6];
    const float* attS2 = (const float*)d_in[7];
    const float* attD2 = (const float*)d_in[8];
    const float* b2    = (const float*)d_in[9];

    const int E = in_sizes[1] / 2;
    const int* src = ei;
    const int* dst = ei + E;

    float* out = (float*)d_out;
    float* f = (float*)d_ws;
    float* h1   = f;  f += (size_t)N_NODES * 64;
    float* aS1  = f;  f += (size_t)N_NODES * 8;
    float* aD1  = f;  f += (size_t)N_NODES * 8;
    float* helu = f;  f += (size_t)N_NODES * 64;
    float* h2   = f;  f += (size_t)N_NODES * 40;
    float* a2s  = f;  f += (size_t)N_NODES;
    float* a2d  = f;  f += (size_t)N_NODES;
    int* ip = (int*)f;
    int* deg      = ip;  ip += N_NODES;
    int* scanned  = ip;  ip += N_NODES;
    int* cum      = ip;  ip += N_NODES;
    int* cursor   = ip;  ip += N_NODES;
    int* partials = ip;  ip += 256;
    int* ssrc     = ip;  ip += E;

    const int nScanBlocks = (N_NODES + 255) / 256;   // 196
    const int eBlocks = (E + 255) / 256;

    // ---- CSR build (independent of gemm1; same graph serves both layers)
    hipMemsetAsync(deg, 0, N_NODES * sizeof(int), stream);
    k_count<<<eBlocks, 256, 0, stream>>>(dst, E, deg);
    k_scan_block<<<nScanBlocks, 256, 0, stream>>>(deg, scanned, partials, N_NODES);
    k_scan_partials<<<1, 256, 0, stream>>>(partials, nScanBlocks);
    k_scan_add<<<nScanBlocks, 256, 0, stream>>>(scanned, partials, deg, cum, cursor, N_NODES);
    k_scatter<<<eBlocks, 256, 0, stream>>>(src, dst, E, cursor, ssrc);

    // ---- Layer 1
    k_gemm1<<<N_NODES / 16, 256, 0, stream>>>(x, W1, attS1, attD1, h1, aS1, aD1);
    k_agg1<<<(N_NODES + 3) / 4, 256, 0, stream>>>(cum, ssrc, aS1, aD1, h1, b1, helu);

    // ---- Layer 2
    k_gemm2<<<N_NODES / 4, 256, 0, stream>>>(helu, W2, attS2, attD2, h2, a2s, a2d);
    k_agg2<<<(N_NODES + 3) / 4, 256, 0, stream>>>(cum, ssrc, a2s, a2d, h2, b2, out);
}

// Round 3
// 483.703 us; speedup vs baseline: 11.4289x; 1.2504x over previous
//
#include <hip/hip_runtime.h>
#include <math.h>

#define N_NODES 50000
#define IN_CH   512
#define HID     8
#define HEADS   8
#define C1      64      // HEADS*HID
#define OUT_CH  40
#define NEG_SLOPE 0.2f

__device__ __forceinline__ float leaky(float v) { return v > 0.f ? v : NEG_SLOPE * v; }

// ---------------------------------------------------------------------------
// K1: fused  h1 = (x @ W1) / rowsum(x);  per-(node,head) logits aS/aD.
// block = 256 (4 waves), 16 rows per block, each wave handles 4 rows.
// ---------------------------------------------------------------------------
__global__ __launch_bounds__(256) void k_gemm1(
    const float* __restrict__ x, const float* __restrict__ W1,
    const float* __restrict__ attS, const float* __restrict__ attD,
    float* __restrict__ h1, float* __restrict__ aS, float* __restrict__ aD)
{
    __shared__ float xs[16][IN_CH];
    const int tid = threadIdx.x;
    const int j   = tid & 63;     // output column 0..63
    const int w   = tid >> 6;     // wave id 0..3
    const int rowBase = blockIdx.x * 16;

    // stage 16 rows of x (16*512 floats) coalesced as float4
    {
        const float4* xg  = (const float4*)(x + (size_t)rowBase * IN_CH);
        float4*       xls = (float4*)(&xs[0][0]);
        #pragma unroll
        for (int i = 0; i < 8; ++i)
            xls[tid + i * 256] = xg[tid + i * 256];
    }
    __syncthreads();

    const int r0 = w * 4;         // this wave's first row slot

    // row sums (lane-parallel + butterfly)
    float rs[4];
    #pragma unroll
    for (int m = 0; m < 4; ++m) {
        const float4* p = (const float4*)(&xs[r0 + m][j * 8]);
        float4 a = p[0], b = p[1];
        float s = a.x + a.y + a.z + a.w + b.x + b.y + b.z + b.w;
        #pragma unroll
        for (int off = 32; off; off >>= 1) s += __shfl_xor(s, off, 64);
        rs[m] = fmaxf(s, 1e-8f);
    }

    float acc0 = 0.f, acc1 = 0.f, acc2 = 0.f, acc3 = 0.f;
    #pragma unroll 4
    for (int k4 = 0; k4 < IN_CH / 4; ++k4) {
        const int k = k4 * 4;
        const float w0  = W1[(k + 0) * 64 + j];
        const float w1_ = W1[(k + 1) * 64 + j];
        const float w2_ = W1[(k + 2) * 64 + j];
        const float w3_ = W1[(k + 3) * 64 + j];
        float4 v;
        v = *(const float4*)(&xs[r0 + 0][k]);
        acc0 = fmaf(v.x, w0, fmaf(v.y, w1_, fmaf(v.z, w2_, fmaf(v.w, w3_, acc0))));
        v = *(const float4*)(&xs[r0 + 1][k]);
        acc1 = fmaf(v.x, w0, fmaf(v.y, w1_, fmaf(v.z, w2_, fmaf(v.w, w3_, acc1))));
        v = *(const float4*)(&xs[r0 + 2][k]);
        acc2 = fmaf(v.x, w0, fmaf(v.y, w1_, fmaf(v.z, w2_, fmaf(v.w, w3_, acc2))));
        v = *(const float4*)(&xs[r0 + 3][k]);
        acc3 = fmaf(v.x, w0, fmaf(v.y, w1_, fmaf(v.z, w2_, fmaf(v.w, w3_, acc3))));
    }

    const float attSj = attS[j];
    const float attDj = attD[j];
    float accs[4] = {acc0, acc1, acc2, acc3};

    #pragma unroll
    for (int m = 0; m < 4; ++m) {
        const int row = rowBase + r0 + m;
        const float val = accs[m] / rs[m];
        float vs = val * attSj;
        float vd = val * attDj;
        // reduce within 8-lane head group; butterfly -> all 8 lanes hold the sum
        #pragma unroll
        for (int off = 4; off; off >>= 1) {
            vs += __shfl_xor(vs, off, 64);
            vd += __shfl_xor(vd, off, 64);
        }
        h1[(size_t)row * 64 + j] = val;
        if ((j & 7) == 0) {
            const int hh = j >> 3;
            aS[(size_t)row * 8 + hh] = vs;
            aD[(size_t)row * 8 + hh] = vd;
        }
    }
}

// ---------------------------------------------------------------------------
// CSR build: count -> 2-level scan -> scatter (src ids bucketed by dst)
// ---------------------------------------------------------------------------
__global__ __launch_bounds__(256) void k_count(
    const int* __restrict__ dst, int E, int* __restrict__ deg)
{
    const int i = blockIdx.x * 256 + threadIdx.x;
    if (i < E) atomicAdd(&deg[dst[i]], 1);
}

__global__ __launch_bounds__(256) void k_scan_block(
    const int* __restrict__ deg, int* __restrict__ scanned,
    int* __restrict__ partials, int n)
{
    __shared__ int tmp[256];
    const int t = threadIdx.x;
    const int idx = blockIdx.x * 256 + t;
    tmp[t] = (idx < n) ? deg[idx] : 0;
    __syncthreads();
    #pragma unroll
    for (int off = 1; off < 256; off <<= 1) {
        int xv = (t >= off) ? tmp[t - off] : 0;
        __syncthreads();
        tmp[t] += xv;
        __syncthreads();
    }
    if (idx < n) scanned[idx] = tmp[t];
    if (t == 255) partials[blockIdx.x] = tmp[255];
}

__global__ __launch_bounds__(256) void k_scan_partials(
    int* __restrict__ partials, int n)
{
    __shared__ int tmp[256];
    const int t = threadIdx.x;
    tmp[t] = (t < n) ? partials[t] : 0;
    __syncthreads();
    #pragma unroll
    for (int off = 1; off < 256; off <<= 1) {
        int xv = (t >= off) ? tmp[t - off] : 0;
        __syncthreads();
        tmp[t] += xv;
        __syncthreads();
    }
    if (t < n) partials[t] = tmp[t];
}

__global__ __launch_bounds__(256) void k_scan_add(
    const int* __restrict__ scanned, const int* __restrict__ partials,
    const int* __restrict__ deg, int* __restrict__ cum,
    int* __restrict__ cursor, int n)
{
    const int idx = blockIdx.x * 256 + threadIdx.x;
    if (idx >= n) return;
    const int base = blockIdx.x ? partials[blockIdx.x - 1] : 0;
    const int inc = scanned[idx] + base;
    cum[idx] = inc;               // inclusive cumulative degree
    cursor[idx] = inc - deg[idx]; // exclusive start, doubles as scatter cursor
}

__global__ __launch_bounds__(256) void k_scatter(
    const int* __restrict__ src, const int* __restrict__ dst, int E,
    int* __restrict__ cursor, int* __restrict__ ssrc)
{
    const int i = blockIdx.x * 256 + threadIdx.x;
    if (i >= E) return;
    const int pos = atomicAdd(&cursor[dst[i]], 1);
    ssrc[pos] = src[i];
}

// ---------------------------------------------------------------------------
// Edge-weight precompute, layer 1: thread = (edge, head)
// ---------------------------------------------------------------------------
__global__ __launch_bounds__(256) void k_wt1(
    const int* __restrict__ src, const int* __restrict__ dst, int E,
    const float* __restrict__ aS, const float* __restrict__ aD,
    const int* __restrict__ ssrc_unused,
    float* __restrict__ ew)
{
    const int idx = blockIdx.x * 256 + threadIdx.x;
    if (idx >= E * 8) return;
    const int e = idx >> 3;
    const int h = idx & 7;
    const int s = src[e];
    const int d = dst[e];
    ew[idx] = expf(leaky(aS[(size_t)s * 8 + h] + aD[(size_t)d * 8 + h]));
}

// NOTE: weights must be in CSR edge order (index k of ssrc), not original
// edge order! Compute them per CSR slot instead: we need dst of slot k.
// Simpler: also scatter the ORIGINAL edge id, then wt kernels index by slot.
__global__ __launch_bounds__(256) void k_scatter2(
    const int* __restrict__ src, const int* __restrict__ dst, int E,
    int* __restrict__ cursor, int* __restrict__ ssrc, int* __restrict__ sdst)
{
    const int i = blockIdx.x * 256 + threadIdx.x;
    if (i >= E) return;
    const int d = dst[i];
    const int pos = atomicAdd(&cursor[d], 1);
    ssrc[pos] = src[i];
    sdst[pos] = d;
}

// weights in CSR slot order, layer 1: thread = (slot, head)
__global__ __launch_bounds__(256) void k_wt1_csr(
    const int* __restrict__ ssrc, const int* __restrict__ sdst, int E,
    const float* __restrict__ aS, const float* __restrict__ aD,
    float* __restrict__ ew)
{
    const int idx = blockIdx.x * 256 + threadIdx.x;
    if (idx >= E * 8) return;
    const int k = idx >> 3;
    const int h = idx & 7;
    const int s = ssrc[k];
    const int d = sdst[k];
    ew[idx] = expf(leaky(aS[(size_t)s * 8 + h] + aD[(size_t)d * 8 + h]));
}

// weights in CSR slot order, layer 2: thread = slot
__global__ __launch_bounds__(256) void k_wt2_csr(
    const int* __restrict__ ssrc, const int* __restrict__ sdst, int E,
    const float* __restrict__ a2s, const float* __restrict__ a2d,
    float* __restrict__ ew)
{
    const int k = blockIdx.x * 256 + threadIdx.x;
    if (k >= E) return;
    ew[k] = expf(leaky(a2s[ssrc[k]] + a2d[sdst[k]]));
}

// ---------------------------------------------------------------------------
// K-AGG1: one wave per dst node; lane = channel; wave-uniform scalar edge walk.
// ---------------------------------------------------------------------------
__global__ __launch_bounds__(256) void k_agg1(
    const int* __restrict__ cum, const int* __restrict__ ssrc,
    const float* __restrict__ ew,
    const float* __restrict__ aS, const float* __restrict__ aD,
    const float* __restrict__ h1, const float* __restrict__ b1,
    float* __restrict__ helu)
{
    const int lane = threadIdx.x & 63;
    const int node = __builtin_amdgcn_readfirstlane(blockIdx.x * 4 + (threadIdx.x >> 6));
    const int h = lane >> 3;

    const int start = node ? cum[node - 1] : 0;
    const int end   = cum[node];

    // self loop
    const float e0 = expf(leaky(aS[(size_t)node * 8 + h] + aD[(size_t)node * 8 + h]));
    float acc = e0 * h1[(size_t)node * 64 + lane];
    float den = e0;

    #pragma unroll 4
    for (int k = start; k < end; ++k) {
        const int s   = ssrc[k];                    // wave-uniform -> s_load
        const float w = ew[(size_t)k * 8 + h];      // saddr + small voffset
        acc = fmaf(w, h1[(size_t)s * 64 + lane], acc);
        den += w;
    }

    const float v = acc / (den + 1e-16f) + b1[lane];
    helu[(size_t)node * 64 + lane] = v > 0.f ? v : expm1f(v);
}

// ---------------------------------------------------------------------------
// K4: h2 = helu @ W2 (64x40); layer-2 logits a2s/a2d.
// ---------------------------------------------------------------------------
__global__ __launch_bounds__(256) void k_gemm2(
    const float* __restrict__ helu, const float* __restrict__ W2,
    const float* __restrict__ attS2, const float* __restrict__ attD2,
    float* __restrict__ h2, float* __restrict__ a2s, float* __restrict__ a2d)
{
    __shared__ float w2s[64 * 40];
    __shared__ float xs[4][64];
    const int tid = threadIdx.x;
    for (int i = tid; i < 64 * 40; i += 256) w2s[i] = W2[i];
    const int rowBase = blockIdx.x * 4;
    xs[tid >> 6][tid & 63] = helu[(size_t)rowBase * 64 + tid];
    __syncthreads();

    const int w = tid >> 6;
    const int j = tid & 63;
    const int row = rowBase + w;

    float acc = 0.f;
    if (j < OUT_CH) {
        #pragma unroll
        for (int k = 0; k < 64; ++k)
            acc = fmaf(xs[w][k], w2s[k * 40 + j], acc);
    }
    float vs = (j < OUT_CH) ? acc * attS2[j] : 0.f;
    float vd = (j < OUT_CH) ? acc * attD2[j] : 0.f;
    #pragma unroll
    for (int off = 32; off; off >>= 1) {
        vs += __shfl_xor(vs, off, 64);
        vd += __shfl_xor(vd, off, 64);
    }
    if (j < OUT_CH) h2[(size_t)row * 40 + j] = acc;
    if (j == 0) {
        a2s[row] = vs;
        a2d[row] = vd;
    }
}

// ---------------------------------------------------------------------------
// K-AGG2: one wave per dst node, lanes 0..39 = channels; scalar edge walk.
// ---------------------------------------------------------------------------
__global__ __launch_bounds__(256) void k_agg2(
    const int* __restrict__ cum, const int* __restrict__ ssrc,
    const float* __restrict__ ew,
    const float* __restrict__ a2s, const float* __restrict__ a2d,
    const float* __restrict__ h2, const float* __restrict__ b2,
    float* __restrict__ out)
{
    const int lane = threadIdx.x & 63;
    const int node = __builtin_amdgcn_readfirstlane(blockIdx.x * 4 + (threadIdx.x >> 6));

    const int start = node ? cum[node - 1] : 0;
    const int end   = cum[node];

    const float e0 = expf(leaky(a2s[node] + a2d[node]));
    float acc = (lane < OUT_CH) ? e0 * h2[(size_t)node * 40 + lane] : 0.f;
    float den = e0;

    #pragma unroll 4
    for (int k = start; k < end; ++k) {
        const int s   = ssrc[k];                    // wave-uniform -> s_load
        const float w = ew[k];                      // wave-uniform scalar
        const float hv = (lane < OUT_CH) ? h2[(size_t)s * 40 + lane] : 0.f;
        acc = fmaf(w, hv, acc);
        den += w;
    }

    if (lane < OUT_CH)
        out[(size_t)node * OUT_CH + lane] = acc / (den + 1e-16f) + b2[lane];
}

// ---------------------------------------------------------------------------
extern "C" void kernel_launch(void* const* d_in, const int* in_sizes, int n_in,
                              void* d_out, int out_size, void* d_ws, size_t ws_size,
                              hipStream_t stream)
{
    const float* x     = (const float*)d_in[0];
    const int*   ei    = (const int*)d_in[1];
    const float* W1    = (const float*)d_in[2];
    const float* attS1 = (const float*)d_in[3];
    const float* attD1 = (const float*)d_in[4];
    const float* b1    = (const float*)d_in[5];
    const float* W2    = (const float*)d_in[6];
    const float* attS2 = (const float*)d_in[7];
    const float* attD2 = (const float*)d_in[8];
    const float* b2    = (const float*)d_in[9];

    const int E = in_sizes[1] / 2;
    const int* src = ei;
    const int* dst = ei + E;

    float* out = (float*)d_out;
    float* f = (float*)d_ws;
    float* h1   = f;  f += (size_t)N_NODES * 64;
    float* aS1  = f;  f += (size_t)N_NODES * 8;
    float* aD1  = f;  f += (size_t)N_NODES * 8;
    float* helu = f;  f += (size_t)N_NODES * 64;
    float* h2   = f;  f += (size_t)N_NODES * 40;
    float* a2s  = f;  f += (size_t)N_NODES;
    float* a2d  = f;  f += (size_t)N_NODES;
    float* ew1  = f;  f += (size_t)E * 8;       // layer-1 weights [E][8]
    float* ew2  = ew1;                          // layer-2 aliases layer-1 (dead by then)
    int* ip = (int*)(f);
    int* deg      = ip;  ip += N_NODES;
    int* scanned  = ip;  ip += N_NODES;
    int* cum      = ip;  ip += N_NODES;
    int* cursor   = ip;  ip += N_NODES;
    int* partials = ip;  ip += 256;
    int* ssrc     = ip;  ip += E;
    int* sdst     = ip;  ip += E;

    const int nScanBlocks = (N_NODES + 255) / 256;   // 196
    const int eBlocks = (E + 255) / 256;

    // ---- CSR build (same graph serves both layers)
    hipMemsetAsync(deg, 0, N_NODES * sizeof(int), stream);
    k_count<<<eBlocks, 256, 0, stream>>>(dst, E, deg);
    k_scan_block<<<nScanBlocks, 256, 0, stream>>>(deg, scanned, partials, N_NODES);
    k_scan_partials<<<1, 256, 0, stream>>>(partials, nScanBlocks);
    k_scan_add<<<nScanBlocks, 256, 0, stream>>>(scanned, partials, deg, cum, cursor, N_NODES);
    k_scatter2<<<eBlocks, 256, 0, stream>>>(src, dst, E, cursor, ssrc, sdst);

    // ---- Layer 1
    k_gemm1<<<N_NODES / 16, 256, 0, stream>>>(x, W1, attS1, attD1, h1, aS1, aD1);
    k_wt1_csr<<<(E * 8 + 255) / 256, 256, 0, stream>>>(ssrc, sdst, E, aS1, aD1, ew1);
    k_agg1<<<N_NODES / 4, 256, 0, stream>>>(cum, ssrc, ew1, aS1, aD1, h1, b1, helu);

    // ---- Layer 2
    k_gemm2<<<N_NODES / 4, 256, 0, stream>>>(helu, W2, attS2, attD2, h2, a2s, a2d);
    k_wt2_csr<<<eBlocks, 256, 0, stream>>>(ssrc, sdst, E, a2s, a2d, ew2);
    k_agg2<<<N_NODES / 4, 256, 0, stream>>>(cum, ssrc, ew2, a2s, a2d, h2, b2, out);
}

// Round 4
// 395.613 us; speedup vs baseline: 13.9738x; 1.2227x over previous
//
#include <hip/hip_runtime.h>
#include <math.h>

#define N_NODES 50000
#define IN_CH   512
#define HID     8
#define HEADS   8
#define C1      64      // HEADS*HID
#define OUT_CH  40
#define NEG_SLOPE 0.2f
#define NB      ((N_NODES + 255) / 256)   // 196 coarse buckets (dst>>8)
#define TILE    4096                      // edges per k_part block

__device__ __forceinline__ float leaky(float v) { return v > 0.f ? v : NEG_SLOPE * v; }

// ---------------------------------------------------------------------------
// K1: fused  h1 = (x @ W1) / rowsum(x);  per-(node,head) logits aS/aD.
// ---------------------------------------------------------------------------
__global__ __launch_bounds__(256) void k_gemm1(
    const float* __restrict__ x, const float* __restrict__ W1,
    const float* __restrict__ attS, const float* __restrict__ attD,
    float* __restrict__ h1, float* __restrict__ aS, float* __restrict__ aD)
{
    __shared__ float xs[16][IN_CH];
    const int tid = threadIdx.x;
    const int j   = tid & 63;     // output column 0..63
    const int w   = tid >> 6;     // wave id 0..3
    const int rowBase = blockIdx.x * 16;

    {
        const float4* xg  = (const float4*)(x + (size_t)rowBase * IN_CH);
        float4*       xls = (float4*)(&xs[0][0]);
        #pragma unroll
        for (int i = 0; i < 8; ++i)
            xls[tid + i * 256] = xg[tid + i * 256];
    }
    __syncthreads();

    const int r0 = w * 4;

    float rs[4];
    #pragma unroll
    for (int m = 0; m < 4; ++m) {
        const float4* p = (const float4*)(&xs[r0 + m][j * 8]);
        float4 a = p[0], b = p[1];
        float s = a.x + a.y + a.z + a.w + b.x + b.y + b.z + b.w;
        #pragma unroll
        for (int off = 32; off; off >>= 1) s += __shfl_xor(s, off, 64);
        rs[m] = fmaxf(s, 1e-8f);
    }

    float acc0 = 0.f, acc1 = 0.f, acc2 = 0.f, acc3 = 0.f;
    #pragma unroll 4
    for (int k4 = 0; k4 < IN_CH / 4; ++k4) {
        const int k = k4 * 4;
        const float w0  = W1[(k + 0) * 64 + j];
        const float w1_ = W1[(k + 1) * 64 + j];
        const float w2_ = W1[(k + 2) * 64 + j];
        const float w3_ = W1[(k + 3) * 64 + j];
        float4 v;
        v = *(const float4*)(&xs[r0 + 0][k]);
        acc0 = fmaf(v.x, w0, fmaf(v.y, w1_, fmaf(v.z, w2_, fmaf(v.w, w3_, acc0))));
        v = *(const float4*)(&xs[r0 + 1][k]);
        acc1 = fmaf(v.x, w0, fmaf(v.y, w1_, fmaf(v.z, w2_, fmaf(v.w, w3_, acc1))));
        v = *(const float4*)(&xs[r0 + 2][k]);
        acc2 = fmaf(v.x, w0, fmaf(v.y, w1_, fmaf(v.z, w2_, fmaf(v.w, w3_, acc2))));
        v = *(const float4*)(&xs[r0 + 3][k]);
        acc3 = fmaf(v.x, w0, fmaf(v.y, w1_, fmaf(v.z, w2_, fmaf(v.w, w3_, acc3))));
    }

    const float attSj = attS[j];
    const float attDj = attD[j];
    float accs[4] = {acc0, acc1, acc2, acc3};

    #pragma unroll
    for (int m = 0; m < 4; ++m) {
        const int row = rowBase + r0 + m;
        const float val = accs[m] / rs[m];
        float vs = val * attSj;
        float vd = val * attDj;
        #pragma unroll
        for (int off = 4; off; off >>= 1) {
            vs += __shfl_xor(vs, off, 64);
            vd += __shfl_xor(vd, off, 64);
        }
        h1[(size_t)row * 64 + j] = val;
        if ((j & 7) == 0) {
            const int hh = j >> 3;
            aS[(size_t)row * 8 + hh] = vs;
            aD[(size_t)row * 8 + hh] = vd;
        }
    }
}

// ---------------------------------------------------------------------------
// CSR build step 1: per-dst degree count
// ---------------------------------------------------------------------------
__global__ __launch_bounds__(256) void k_count(
    const int* __restrict__ dst, int E, int* __restrict__ deg)
{
    const int i = blockIdx.x * 256 + threadIdx.x;
    if (i < E) atomicAdd(&deg[dst[i]], 1);
}

__global__ __launch_bounds__(256) void k_scan_block(
    const int* __restrict__ deg, int* __restrict__ scanned,
    int* __restrict__ partials, int n)
{
    __shared__ int tmp[256];
    const int t = threadIdx.x;
    const int idx = blockIdx.x * 256 + t;
    tmp[t] = (idx < n) ? deg[idx] : 0;
    __syncthreads();
    #pragma unroll
    for (int off = 1; off < 256; off <<= 1) {
        int xv = (t >= off) ? tmp[t - off] : 0;
        __syncthreads();
        tmp[t] += xv;
        __syncthreads();
    }
    if (idx < n) scanned[idx] = tmp[t];
    if (t == 255) partials[blockIdx.x] = tmp[255];
}

__global__ __launch_bounds__(256) void k_scan_partials(
    int* __restrict__ partials, int n)
{
    __shared__ int tmp[256];
    const int t = threadIdx.x;
    tmp[t] = (t < n) ? partials[t] : 0;
    __syncthreads();
    #pragma unroll
    for (int off = 1; off < 256; off <<= 1) {
        int xv = (t >= off) ? tmp[t - off] : 0;
        __syncthreads();
        tmp[t] += xv;
        __syncthreads();
    }
    if (t < n) partials[t] = tmp[t];
}

// cum (inclusive) + coarse-bucket cursors init
__global__ __launch_bounds__(256) void k_scan_add(
    const int* __restrict__ scanned, const int* __restrict__ partials,
    int* __restrict__ cum, int* __restrict__ coarseCur, int n)
{
    const int idx = blockIdx.x * 256 + threadIdx.x;
    if (idx >= n) return;
    const int base = blockIdx.x ? partials[blockIdx.x - 1] : 0;
    const int inc = scanned[idx] + base;
    cum[idx] = inc;
    if (idx == 0) coarseCur[0] = 0;
    if ((idx & 255) == 255 && (idx >> 8) + 1 < NB)
        coarseCur[(idx >> 8) + 1] = inc;
}

// ---------------------------------------------------------------------------
// Pass A: coarse partition of (src,dst) pairs by dst>>8 with LDS reorder
// so global writes are bucket-contiguous runs.
// ---------------------------------------------------------------------------
__global__ __launch_bounds__(256) void k_part(
    const int* __restrict__ src, const int* __restrict__ dst, int E,
    int* __restrict__ coarseCur, int2* __restrict__ pairs)
{
    __shared__ int  hist[256];
    __shared__ int  scn[256];
    __shared__ int  offs[256];
    __shared__ int2 pairBuf[TILE];

    const int t = threadIdx.x;
    const int tileBase = blockIdx.x * TILE;
    const int n = min(TILE, E - tileBase);

    hist[t] = 0;
    __syncthreads();

    for (int e = t; e < n; e += 256)
        atomicAdd(&hist[dst[tileBase + e] >> 8], 1);
    __syncthreads();

    // inclusive scan of hist -> scn
    scn[t] = hist[t];
    __syncthreads();
    #pragma unroll
    for (int off = 1; off < 256; off <<= 1) {
        int xv = (t >= off) ? scn[t - off] : 0;
        __syncthreads();
        scn[t] += xv;
        __syncthreads();
    }

    // reserve global runs; hist becomes local placement cursor (excl start)
    {
        const int h  = hist[t];
        const int ls = scn[t] - h;
        int off = 0;
        if (h > 0) {
            const int gbase = atomicAdd(&coarseCur[t], h);
            off = gbase - ls;
        }
        offs[t] = off;
        hist[t] = ls;
    }
    __syncthreads();

    // place into LDS, bucket-sorted
    for (int e = t; e < n; e += 256) {
        const int s = src[tileBase + e];
        const int d = dst[tileBase + e];
        const int pos = atomicAdd(&hist[d >> 8], 1);
        pairBuf[pos] = make_int2(s, d);
    }
    __syncthreads();

    // flush: consecutive LDS slots -> consecutive global slots per bucket
    for (int i = t; i < n; i += 256) {
        const int2 p = pairBuf[i];
        pairs[i + offs[p.y >> 8]] = p;
    }
}

// ---------------------------------------------------------------------------
// Pass B: fine scatter within each coarse bucket. One workgroup per bucket;
// per-dst cursors live in LDS; write window ~32KB -> single-XCD L2.
// ---------------------------------------------------------------------------
__global__ __launch_bounds__(256) void k_fine(
    const int* __restrict__ cum, const int2* __restrict__ pairs,
    int* __restrict__ ssrc)
{
    __shared__ int cur[256];
    const int b = blockIdx.x;
    const int t = threadIdx.x;
    const int dbase = b << 8;
    const int nd = min(256, N_NODES - dbase);

    if (t < nd) cur[t] = (dbase + t) ? cum[dbase + t - 1] : 0;
    __syncthreads();

    const int lo = dbase ? cum[dbase - 1] : 0;
    const int hi = cum[dbase + nd - 1];

    for (int j = lo + t; j < hi; j += 256) {
        const int2 p = pairs[j];
        const int pos = atomicAdd(&cur[p.y - dbase], 1);
        ssrc[pos] = p.x;
    }
}

// ---------------------------------------------------------------------------
// Edge weights layer 1, CSR slot order; wave per node (dst uniform).
// lane = (slotOffset*8 + head)
// ---------------------------------------------------------------------------
__global__ __launch_bounds__(256) void k_wt1_node(
    const int* __restrict__ cum, const int* __restrict__ ssrc,
    const float* __restrict__ aS, const float* __restrict__ aD,
    float* __restrict__ ew)
{
    const int lane = threadIdx.x & 63;
    const int node = __builtin_amdgcn_readfirstlane(blockIdx.x * 4 + (threadIdx.x >> 6));
    const int start = node ? cum[node - 1] : 0;
    const int end   = cum[node];
    const int h = lane & 7;
    const float aDn = aD[(size_t)node * 8 + h];

    for (int k0 = start; k0 < end; k0 += 8) {
        const int slot = k0 + (lane >> 3);
        if (slot < end) {
            const int s = ssrc[slot];
            ew[(size_t)slot * 8 + h] = expf(leaky(aS[(size_t)s * 8 + h] + aDn));
        }
    }
}

// ---------------------------------------------------------------------------
// Edge weights layer 2, CSR slot order; wave per node, lane = slot offset.
// ---------------------------------------------------------------------------
__global__ __launch_bounds__(256) void k_wt2_node(
    const int* __restrict__ cum, const int* __restrict__ ssrc,
    const float* __restrict__ a2s, const float* __restrict__ a2d,
    float* __restrict__ ew)
{
    const int lane = threadIdx.x & 63;
    const int node = __builtin_amdgcn_readfirstlane(blockIdx.x * 4 + (threadIdx.x >> 6));
    const int start = node ? cum[node - 1] : 0;
    const int end   = cum[node];
    const float aDn = a2d[node];

    for (int k = start + lane; k < end; k += 64) {
        const int s = ssrc[k];
        ew[k] = expf(leaky(a2s[s] + aDn));
    }
}

// ---------------------------------------------------------------------------
// K-AGG1: one wave per dst node; lane = channel; wave-uniform scalar edge walk.
// ---------------------------------------------------------------------------
__global__ __launch_bounds__(256) void k_agg1(
    const int* __restrict__ cum, const int* __restrict__ ssrc,
    const float* __restrict__ ew,
    const float* __restrict__ aS, const float* __restrict__ aD,
    const float* __restrict__ h1, const float* __restrict__ b1,
    float* __restrict__ helu)
{
    const int lane = threadIdx.x & 63;
    const int node = __builtin_amdgcn_readfirstlane(blockIdx.x * 4 + (threadIdx.x >> 6));
    const int h = lane >> 3;

    const int start = node ? cum[node - 1] : 0;
    const int end   = cum[node];

    const float e0 = expf(leaky(aS[(size_t)node * 8 + h] + aD[(size_t)node * 8 + h]));
    float acc = e0 * h1[(size_t)node * 64 + lane];
    float den = e0;

    #pragma unroll 4
    for (int k = start; k < end; ++k) {
        const int s   = ssrc[k];
        const float w = ew[(size_t)k * 8 + h];
        acc = fmaf(w, h1[(size_t)s * 64 + lane], acc);
        den += w;
    }

    const float v = acc / (den + 1e-16f) + b1[lane];
    helu[(size_t)node * 64 + lane] = v > 0.f ? v : expm1f(v);
}

// ---------------------------------------------------------------------------
// K4: h2 = helu @ W2 (64x40); layer-2 logits a2s/a2d.
// ---------------------------------------------------------------------------
__global__ __launch_bounds__(256) void k_gemm2(
    const float* __restrict__ helu, const float* __restrict__ W2,
    const float* __restrict__ attS2, const float* __restrict__ attD2,
    float* __restrict__ h2, float* __restrict__ a2s, float* __restrict__ a2d)
{
    __shared__ float w2s[64 * 40];
    __shared__ float xs[4][64];
    const int tid = threadIdx.x;
    for (int i = tid; i < 64 * 40; i += 256) w2s[i] = W2[i];
    const int rowBase = blockIdx.x * 4;
    xs[tid >> 6][tid & 63] = helu[(size_t)rowBase * 64 + tid];
    __syncthreads();

    const int w = tid >> 6;
    const int j = tid & 63;
    const int row = rowBase + w;

    float acc = 0.f;
    if (j < OUT_CH) {
        #pragma unroll
        for (int k = 0; k < 64; ++k)
            acc = fmaf(xs[w][k], w2s[k * 40 + j], acc);
    }
    float vs = (j < OUT_CH) ? acc * attS2[j] : 0.f;
    float vd = (j < OUT_CH) ? acc * attD2[j] : 0.f;
    #pragma unroll
    for (int off = 32; off; off >>= 1) {
        vs += __shfl_xor(vs, off, 64);
        vd += __shfl_xor(vd, off, 64);
    }
    if (j < OUT_CH) h2[(size_t)row * 40 + j] = acc;
    if (j == 0) {
        a2s[row] = vs;
        a2d[row] = vd;
    }
}

// ---------------------------------------------------------------------------
// K-AGG2: one wave per dst node, lanes 0..39 = channels; scalar edge walk.
// ---------------------------------------------------------------------------
__global__ __launch_bounds__(256) void k_agg2(
    const int* __restrict__ cum, const int* __restrict__ ssrc,
    const float* __restrict__ ew,
    const float* __restrict__ a2s, const float* __restrict__ a2d,
    const float* __restrict__ h2, const float* __restrict__ b2,
    float* __restrict__ out)
{
    const int lane = threadIdx.x & 63;
    const int node = __builtin_amdgcn_readfirstlane(blockIdx.x * 4 + (threadIdx.x >> 6));

    const int start = node ? cum[node - 1] : 0;
    const int end   = cum[node];

    const float e0 = expf(leaky(a2s[node] + a2d[node]));
    float acc = (lane < OUT_CH) ? e0 * h2[(size_t)node * 40 + lane] : 0.f;
    float den = e0;

    #pragma unroll 4
    for (int k = start; k < end; ++k) {
        const int s   = ssrc[k];
        const float w = ew[k];
        const float hv = (lane < OUT_CH) ? h2[(size_t)s * 40 + lane] : 0.f;
        acc = fmaf(w, hv, acc);
        den += w;
    }

    if (lane < OUT_CH)
        out[(size_t)node * OUT_CH + lane] = acc / (den + 1e-16f) + b2[lane];
}

// ---------------------------------------------------------------------------
extern "C" void kernel_launch(void* const* d_in, const int* in_sizes, int n_in,
                              void* d_out, int out_size, void* d_ws, size_t ws_size,
                              hipStream_t stream)
{
    const float* x     = (const float*)d_in[0];
    const int*   ei    = (const int*)d_in[1];
    const float* W1    = (const float*)d_in[2];
    const float* attS1 = (const float*)d_in[3];
    const float* attD1 = (const float*)d_in[4];
    const float* b1    = (const float*)d_in[5];
    const float* W2    = (const float*)d_in[6];
    const float* attS2 = (const float*)d_in[7];
    const float* attD2 = (const float*)d_in[8];
    const float* b2    = (const float*)d_in[9];

    const int E = in_sizes[1] / 2;
    const int* src = ei;
    const int* dst = ei + E;

    float* out = (float*)d_out;
    float* f = (float*)d_ws;
    float* h1   = f;  f += (size_t)N_NODES * 64;
    float* aS1  = f;  f += (size_t)N_NODES * 8;
    float* aD1  = f;  f += (size_t)N_NODES * 8;
    float* helu = f;  f += (size_t)N_NODES * 64;
    float* h2   = f;  f += (size_t)N_NODES * 40;
    float* a2s  = f;  f += (size_t)N_NODES;
    float* a2d  = f;  f += (size_t)N_NODES;
    float* ew1  = f;  f += (size_t)E * 8;       // layer-1 weights [E][8]
    float* ew2  = ew1;                          // layer-2 aliases layer-1
    int2* pairs = (int2*)f;  f += (size_t)E * 2;
    int* ip = (int*)f;
    int* deg       = ip;  ip += N_NODES;
    int* scanned   = ip;  ip += N_NODES;
    int* cum       = ip;  ip += N_NODES;
    int* partials  = ip;  ip += 256;
    int* coarseCur = ip;  ip += NB;
    int* ssrc      = ip;  ip += E;

    const int nScanBlocks = (N_NODES + 255) / 256;   // 196
    const int eBlocks = (E + 255) / 256;
    const int partBlocks = (E + TILE - 1) / TILE;

    // ---- CSR build (same graph serves both layers)
    hipMemsetAsync(deg, 0, N_NODES * sizeof(int), stream);
    k_count<<<eBlocks, 256, 0, stream>>>(dst, E, deg);
    k_scan_block<<<nScanBlocks, 256, 0, stream>>>(deg, scanned, partials, N_NODES);
    k_scan_partials<<<1, 256, 0, stream>>>(partials, nScanBlocks);
    k_scan_add<<<nScanBlocks, 256, 0, stream>>>(scanned, partials, cum, coarseCur, N_NODES);
    k_part<<<partBlocks, 256, 0, stream>>>(src, dst, E, coarseCur, pairs);
    k_fine<<<NB, 256, 0, stream>>>(cum, pairs, ssrc);

    // ---- Layer 1
    k_gemm1<<<N_NODES / 16, 256, 0, stream>>>(x, W1, attS1, attD1, h1, aS1, aD1);
    k_wt1_node<<<N_NODES / 4, 256, 0, stream>>>(cum, ssrc, aS1, aD1, ew1);
    k_agg1<<<N_NODES / 4, 256, 0, stream>>>(cum, ssrc, ew1, aS1, aD1, h1, b1, helu);

    // ---- Layer 2
    k_gemm2<<<N_NODES / 4, 256, 0, stream>>>(helu, W2, attS2, attD2, h2, a2s, a2d);
    k_wt2_node<<<N_NODES / 4, 256, 0, stream>>>(cum, ssrc, a2s, a2d, ew2);
    k_agg2<<<N_NODES / 4, 256, 0, stream>>>(cum, ssrc, ew2, a2s, a2d, h2, b2, out);
}

// Round 5
// 385.274 us; speedup vs baseline: 14.3487x; 1.0268x over previous
//
#include <hip/hip_runtime.h>
#include <math.h>

#define N_NODES 50000
#define IN_CH   512
#define HID     8
#define HEADS   8
#define C1      64      // HEADS*HID
#define OUT_CH  40
#define NEG_SLOPE 0.2f
#define NB      ((N_NODES + 255) / 256)   // 196 coarse buckets (dst>>8)
#define TILE    4096                      // edges per k_part block

__device__ __forceinline__ float leaky(float v) { return v > 0.f ? v : NEG_SLOPE * v; }

typedef __attribute__((ext_vector_type(8))) short short8;
typedef __attribute__((ext_vector_type(4))) short short4v;
typedef __attribute__((ext_vector_type(4))) float f32x4;

__device__ __forceinline__ unsigned short f2bf(float f) {
    unsigned u = __builtin_bit_cast(unsigned, f);
    u += 0x7FFFu + ((u >> 16) & 1u);          // round-to-nearest-even
    return (unsigned short)(u >> 16);
}
__device__ __forceinline__ float bf2f(unsigned short h) {
    unsigned u = ((unsigned)h) << 16;
    return __builtin_bit_cast(float, u);
}

#define XH_STRIDE_B 272   // bytes per LDS row: 128 bf16 = 256B + 16 pad

// ---------------------------------------------------------------------------
// Pack W1 (512x64 fp32) into MFMA B-fragment order, bf16 hi/lo.
// dst idx = ((k>>5)*64 + col)*32 + (k&31)  -> lane (col,kg) reads 16B contig.
// ---------------------------------------------------------------------------
__global__ __launch_bounds__(256) void k_packW(
    const float* __restrict__ W1, short* __restrict__ bph, short* __restrict__ bpl)
{
    const int idx = blockIdx.x * 256 + threadIdx.x;
    if (idx >= 512 * 64) return;
    const int k = idx >> 6, col = idx & 63;
    const float w = W1[idx];
    const unsigned short hi = f2bf(w);
    const unsigned short lo = f2bf(w - bf2f(hi));
    const int di = ((k >> 5) * 64 + col) * 32 + (k & 31);
    bph[di] = (short)hi;
    bpl[di] = (short)lo;
}

// ---------------------------------------------------------------------------
// K1 (MFMA): h1 = (x @ W1) / rowsum(x), bf16x3 split for fp32-equiv accuracy.
// block = 256 (4 waves); 32 rows x 64 cols per block; wave = 16 rows x 32 cols.
// Epilogue: normalize -> LDS -> coalesced h1 write + aS/aD logits.
// ---------------------------------------------------------------------------
__global__ __launch_bounds__(256) void k_gemm1_mfma(
    const float* __restrict__ x,
    const short* __restrict__ bph, const short* __restrict__ bpl,
    const float* __restrict__ attS, const float* __restrict__ attD,
    float* __restrict__ h1, float* __restrict__ aS, float* __restrict__ aD)
{
    __shared__ unsigned char smem[17536];
    short* xh = (short*)smem;                      // [32] rows x 136 shorts
    short* xl = (short*)(smem + 8704);
    float* rowsum = (float*)(smem + 17408);        // [32]
    float* houtf  = (float*)smem;                  // [32][68] (aliases xh/xl)

    const int tid  = threadIdx.x;
    const int lane = tid & 63;
    const int w    = tid >> 6;
    const int row_off = (w & 1) * 16;
    const int col_off = (w >> 1) * 32;
    const int rowBase = blockIdx.x * 32;

    if (tid < 32) rowsum[tid] = 0.f;
    __syncthreads();

    f32x4 acc0 = {0.f, 0.f, 0.f, 0.f};
    f32x4 acc1 = {0.f, 0.f, 0.f, 0.f};

    const int l15 = lane & 15;
    const int kg  = lane >> 4;
    const int a_base = (l15 + row_off) * XH_STRIDE_B + kg * 16;

    for (int c = 0; c < 4; ++c) {
        // ---- stage chunk c: 32 rows x 128 k, fp32 -> bf16 hi/lo, + rowsum
        #pragma unroll
        for (int i = 0; i < 4; ++i) {
            const int flat = i * 256 + tid;        // float4 slot in 32x128 chunk
            const int row  = flat >> 5;
            const int k4   = flat & 31;
            const int grow = rowBase + row;
            float4 v = make_float4(0.f, 0.f, 0.f, 0.f);
            if (grow < N_NODES)
                v = *(const float4*)(x + (size_t)grow * IN_CH + c * 128 + k4 * 4);
            const unsigned short h0 = f2bf(v.x), h1u = f2bf(v.y),
                                 h2 = f2bf(v.z), h3  = f2bf(v.w);
            short4v hv = { (short)h0, (short)h1u, (short)h2, (short)h3 };
            short4v lv = { (short)f2bf(v.x - bf2f(h0)), (short)f2bf(v.y - bf2f(h1u)),
                           (short)f2bf(v.z - bf2f(h2)), (short)f2bf(v.w - bf2f(h3)) };
            *(short4v*)((char*)xh + row * XH_STRIDE_B + k4 * 8) = hv;
            *(short4v*)((char*)xl + row * XH_STRIDE_B + k4 * 8) = lv;
            atomicAdd(&rowsum[row], v.x + v.y + v.z + v.w);
        }
        __syncthreads();

        // ---- MFMA: 4 k-steps of 32
        #pragma unroll
        for (int kk2 = 0; kk2 < 4; ++kk2) {
            const int kk = c * 4 + kk2;
            const short8 ah = *(const short8*)((const char*)xh + a_base + kk2 * 64);
            const short8 al = *(const short8*)((const char*)xl + a_base + kk2 * 64);
            const int b_idx0 = ((kk * 64 + col_off + l15)) * 32 + kg * 8;
            const int b_idx1 = b_idx0 + 16 * 32;
            const short8 bh0 = *(const short8*)(bph + b_idx0);
            const short8 bl0 = *(const short8*)(bpl + b_idx0);
            const short8 bh1 = *(const short8*)(bph + b_idx1);
            const short8 bl1 = *(const short8*)(bpl + b_idx1);
            acc0 = __builtin_amdgcn_mfma_f32_16x16x32_bf16(ah, bh0, acc0, 0, 0, 0);
            acc1 = __builtin_amdgcn_mfma_f32_16x16x32_bf16(ah, bh1, acc1, 0, 0, 0);
            acc0 = __builtin_amdgcn_mfma_f32_16x16x32_bf16(ah, bl0, acc0, 0, 0, 0);
            acc1 = __builtin_amdgcn_mfma_f32_16x16x32_bf16(ah, bl1, acc1, 0, 0, 0);
            acc0 = __builtin_amdgcn_mfma_f32_16x16x32_bf16(al, bh0, acc0, 0, 0, 0);
            acc1 = __builtin_amdgcn_mfma_f32_16x16x32_bf16(al, bh1, acc1, 0, 0, 0);
        }
        __syncthreads();
    }

    // ---- epilogue: normalize, stash fp32 tile in LDS (aliases xh/xl)
    #pragma unroll
    for (int r = 0; r < 4; ++r) {
        const int row = row_off + kg * 4 + r;   // C/D: row=(lane>>4)*4+reg
        const float rs = fmaxf(rowsum[row], 1e-8f);
        houtf[row * 68 + col_off + l15]      = acc0[r] / rs;
        houtf[row * 68 + col_off + 16 + l15] = acc1[r] / rs;
    }
    __syncthreads();

    // coalesced h1 write
    #pragma unroll
    for (int i = tid; i < 32 * 16; i += 256) {
        const int row = i >> 4, seg = i & 15;
        if (rowBase + row < N_NODES)
            *(float4*)(h1 + (size_t)(rowBase + row) * 64 + seg * 4) =
                *(const float4*)(houtf + row * 68 + seg * 4);
    }

    // logits: thread = (row, head)
    {
        const int row = tid >> 3, hd = tid & 7;
        if (rowBase + row < N_NODES) {
            float vs = 0.f, vd = 0.f;
            #pragma unroll
            for (int e2 = 0; e2 < 8; ++e2) {
                const float hv = houtf[row * 68 + hd * 8 + e2];
                vs = fmaf(hv, attS[hd * 8 + e2], vs);
                vd = fmaf(hv, attD[hd * 8 + e2], vd);
            }
            aS[(size_t)(rowBase + row) * 8 + hd] = vs;
            aD[(size_t)(rowBase + row) * 8 + hd] = vd;
        }
    }
}

// ---------------------------------------------------------------------------
// CSR build step 1: per-dst degree count
// ---------------------------------------------------------------------------
__global__ __launch_bounds__(256) void k_count(
    const int* __restrict__ dst, int E, int* __restrict__ deg)
{
    const int i = blockIdx.x * 256 + threadIdx.x;
    if (i < E) atomicAdd(&deg[dst[i]], 1);
}

__global__ __launch_bounds__(256) void k_scan_block(
    const int* __restrict__ deg, int* __restrict__ scanned,
    int* __restrict__ partials, int n)
{
    __shared__ int tmp[256];
    const int t = threadIdx.x;
    const int idx = blockIdx.x * 256 + t;
    tmp[t] = (idx < n) ? deg[idx] : 0;
    __syncthreads();
    #pragma unroll
    for (int off = 1; off < 256; off <<= 1) {
        int xv = (t >= off) ? tmp[t - off] : 0;
        __syncthreads();
        tmp[t] += xv;
        __syncthreads();
    }
    if (idx < n) scanned[idx] = tmp[t];
    if (t == 255) partials[blockIdx.x] = tmp[255];
}

__global__ __launch_bounds__(256) void k_scan_partials(
    int* __restrict__ partials, int n)
{
    __shared__ int tmp[256];
    const int t = threadIdx.x;
    tmp[t] = (t < n) ? partials[t] : 0;
    __syncthreads();
    #pragma unroll
    for (int off = 1; off < 256; off <<= 1) {
        int xv = (t >= off) ? tmp[t - off] : 0;
        __syncthreads();
        tmp[t] += xv;
        __syncthreads();
    }
    if (t < n) partials[t] = tmp[t];
}

// cum (inclusive) + coarse-bucket cursors init
__global__ __launch_bounds__(256) void k_scan_add(
    const int* __restrict__ scanned, const int* __restrict__ partials,
    int* __restrict__ cum, int* __restrict__ coarseCur, int n)
{
    const int idx = blockIdx.x * 256 + threadIdx.x;
    if (idx >= n) return;
    const int base = blockIdx.x ? partials[blockIdx.x - 1] : 0;
    const int inc = scanned[idx] + base;
    cum[idx] = inc;
    if (idx == 0) coarseCur[0] = 0;
    if ((idx & 255) == 255 && (idx >> 8) + 1 < NB)
        coarseCur[(idx >> 8) + 1] = inc;
}

// ---------------------------------------------------------------------------
// Pass A: coarse partition of (src,dst) pairs by dst>>8 with LDS reorder
// ---------------------------------------------------------------------------
__global__ __launch_bounds__(256) void k_part(
    const int* __restrict__ src, const int* __restrict__ dst, int E,
    int* __restrict__ coarseCur, int2* __restrict__ pairs)
{
    __shared__ int  hist[256];
    __shared__ int  scn[256];
    __shared__ int  offs[256];
    __shared__ int2 pairBuf[TILE];

    const int t = threadIdx.x;
    const int tileBase = blockIdx.x * TILE;
    const int n = min(TILE, E - tileBase);

    hist[t] = 0;
    __syncthreads();

    for (int e = t; e < n; e += 256)
        atomicAdd(&hist[dst[tileBase + e] >> 8], 1);
    __syncthreads();

    scn[t] = hist[t];
    __syncthreads();
    #pragma unroll
    for (int off = 1; off < 256; off <<= 1) {
        int xv = (t >= off) ? scn[t - off] : 0;
        __syncthreads();
        scn[t] += xv;
        __syncthreads();
    }

    {
        const int h  = hist[t];
        const int ls = scn[t] - h;
        int off = 0;
        if (h > 0) {
            const int gbase = atomicAdd(&coarseCur[t], h);
            off = gbase - ls;
        }
        offs[t] = off;
        hist[t] = ls;
    }
    __syncthreads();

    for (int e = t; e < n; e += 256) {
        const int s = src[tileBase + e];
        const int d = dst[tileBase + e];
        const int pos = atomicAdd(&hist[d >> 8], 1);
        pairBuf[pos] = make_int2(s, d);
    }
    __syncthreads();

    for (int i = t; i < n; i += 256) {
        const int2 p = pairBuf[i];
        pairs[i + offs[p.y >> 8]] = p;
    }
}

// ---------------------------------------------------------------------------
// Pass B: fine scatter within each coarse bucket (write window ~1 XCD L2)
// ---------------------------------------------------------------------------
__global__ __launch_bounds__(256) void k_fine(
    const int* __restrict__ cum, const int2* __restrict__ pairs,
    int* __restrict__ ssrc)
{
    __shared__ int cur[256];
    const int b = blockIdx.x;
    const int t = threadIdx.x;
    const int dbase = b << 8;
    const int nd = min(256, N_NODES - dbase);

    if (t < nd) cur[t] = (dbase + t) ? cum[dbase + t - 1] : 0;
    __syncthreads();

    const int lo = dbase ? cum[dbase - 1] : 0;
    const int hi = cum[dbase + nd - 1];

    for (int j = lo + t; j < hi; j += 256) {
        const int2 p = pairs[j];
        const int pos = atomicAdd(&cur[p.y - dbase], 1);
        ssrc[pos] = p.x;
    }
}

// ---------------------------------------------------------------------------
// Edge weights layer 1, CSR slot order; wave per node (dst uniform).
// ---------------------------------------------------------------------------
__global__ __launch_bounds__(256) void k_wt1_node(
    const int* __restrict__ cum, const int* __restrict__ ssrc,
    const float* __restrict__ aS, const float* __restrict__ aD,
    float* __restrict__ ew)
{
    const int lane = threadIdx.x & 63;
    const int node = __builtin_amdgcn_readfirstlane(blockIdx.x * 4 + (threadIdx.x >> 6));
    const int start = node ? cum[node - 1] : 0;
    const int end   = cum[node];
    const int h = lane & 7;
    const float aDn = aD[(size_t)node * 8 + h];

    for (int k0 = start; k0 < end; k0 += 8) {
        const int slot = k0 + (lane >> 3);
        if (slot < end) {
            const int s = ssrc[slot];
            ew[(size_t)slot * 8 + h] = expf(leaky(aS[(size_t)s * 8 + h] + aDn));
        }
    }
}

__global__ __launch_bounds__(256) void k_wt2_node(
    const int* __restrict__ cum, const int* __restrict__ ssrc,
    const float* __restrict__ a2s, const float* __restrict__ a2d,
    float* __restrict__ ew)
{
    const int lane = threadIdx.x & 63;
    const int node = __builtin_amdgcn_readfirstlane(blockIdx.x * 4 + (threadIdx.x >> 6));
    const int start = node ? cum[node - 1] : 0;
    const int end   = cum[node];
    const float aDn = a2d[node];

    for (int k = start + lane; k < end; k += 64) {
        const int s = ssrc[k];
        ew[k] = expf(leaky(a2s[s] + aDn));
    }
}

// ---------------------------------------------------------------------------
// K-AGG1: one wave per dst node; lane = channel; wave-uniform scalar edge walk.
// ---------------------------------------------------------------------------
__global__ __launch_bounds__(256) void k_agg1(
    const int* __restrict__ cum, const int* __restrict__ ssrc,
    const float* __restrict__ ew,
    const float* __restrict__ aS, const float* __restrict__ aD,
    const float* __restrict__ h1, const float* __restrict__ b1,
    float* __restrict__ helu)
{
    const int lane = threadIdx.x & 63;
    const int node = __builtin_amdgcn_readfirstlane(blockIdx.x * 4 + (threadIdx.x >> 6));
    const int h = lane >> 3;

    const int start = node ? cum[node - 1] : 0;
    const int end   = cum[node];

    const float e0 = expf(leaky(aS[(size_t)node * 8 + h] + aD[(size_t)node * 8 + h]));
    float acc = e0 * h1[(size_t)node * 64 + lane];
    float den = e0;

    #pragma unroll 4
    for (int k = start; k < end; ++k) {
        const int s   = ssrc[k];
        const float w = ew[(size_t)k * 8 + h];
        acc = fmaf(w, h1[(size_t)s * 64 + lane], acc);
        den += w;
    }

    const float v = acc / (den + 1e-16f) + b1[lane];
    helu[(size_t)node * 64 + lane] = v > 0.f ? v : expm1f(v);
}

// ---------------------------------------------------------------------------
// K4: h2 = helu @ W2 (64x40); layer-2 logits a2s/a2d.
// ---------------------------------------------------------------------------
__global__ __launch_bounds__(256) void k_gemm2(
    const float* __restrict__ helu, const float* __restrict__ W2,
    const float* __restrict__ attS2, const float* __restrict__ attD2,
    float* __restrict__ h2, float* __restrict__ a2s, float* __restrict__ a2d)
{
    __shared__ float w2s[64 * 40];
    __shared__ float xs[4][64];
    const int tid = threadIdx.x;
    for (int i = tid; i < 64 * 40; i += 256) w2s[i] = W2[i];
    const int rowBase = blockIdx.x * 4;
    xs[tid >> 6][tid & 63] = helu[(size_t)rowBase * 64 + tid];
    __syncthreads();

    const int w = tid >> 6;
    const int j = tid & 63;
    const int row = rowBase + w;

    float acc = 0.f;
    if (j < OUT_CH) {
        #pragma unroll
        for (int k = 0; k < 64; ++k)
            acc = fmaf(xs[w][k], w2s[k * 40 + j], acc);
    }
    float vs = (j < OUT_CH) ? acc * attS2[j] : 0.f;
    float vd = (j < OUT_CH) ? acc * attD2[j] : 0.f;
    #pragma unroll
    for (int off = 32; off; off >>= 1) {
        vs += __shfl_xor(vs, off, 64);
        vd += __shfl_xor(vd, off, 64);
    }
    if (j < OUT_CH) h2[(size_t)row * 40 + j] = acc;
    if (j == 0) {
        a2s[row] = vs;
        a2d[row] = vd;
    }
}

// ---------------------------------------------------------------------------
// K-AGG2: one wave per dst node, lanes 0..39 = channels; scalar edge walk.
// ---------------------------------------------------------------------------
__global__ __launch_bounds__(256) void k_agg2(
    const int* __restrict__ cum, const int* __restrict__ ssrc,
    const float* __restrict__ ew,
    const float* __restrict__ a2s, const float* __restrict__ a2d,
    const float* __restrict__ h2, const float* __restrict__ b2,
    float* __restrict__ out)
{
    const int lane = threadIdx.x & 63;
    const int node = __builtin_amdgcn_readfirstlane(blockIdx.x * 4 + (threadIdx.x >> 6));

    const int start = node ? cum[node - 1] : 0;
    const int end   = cum[node];

    const float e0 = expf(leaky(a2s[node] + a2d[node]));
    float acc = (lane < OUT_CH) ? e0 * h2[(size_t)node * 40 + lane] : 0.f;
    float den = e0;

    #pragma unroll 4
    for (int k = start; k < end; ++k) {
        const int s   = ssrc[k];
        const float w = ew[k];
        const float hv = (lane < OUT_CH) ? h2[(size_t)s * 40 + lane] : 0.f;
        acc = fmaf(w, hv, acc);
        den += w;
    }

    if (lane < OUT_CH)
        out[(size_t)node * OUT_CH + lane] = acc / (den + 1e-16f) + b2[lane];
}

// ---------------------------------------------------------------------------
extern "C" void kernel_launch(void* const* d_in, const int* in_sizes, int n_in,
                              void* d_out, int out_size, void* d_ws, size_t ws_size,
                              hipStream_t stream)
{
    const float* x     = (const float*)d_in[0];
    const int*   ei    = (const int*)d_in[1];
    const float* W1    = (const float*)d_in[2];
    const float* attS1 = (const float*)d_in[3];
    const float* attD1 = (const float*)d_in[4];
    const float* b1    = (const float*)d_in[5];
    const float* W2    = (const float*)d_in[6];
    const float* attS2 = (const float*)d_in[7];
    const float* attD2 = (const float*)d_in[8];
    const float* b2    = (const float*)d_in[9];

    const int E = in_sizes[1] / 2;
    const int* src = ei;
    const int* dst = ei + E;

    float* out = (float*)d_out;
    float* f = (float*)d_ws;
    float* h1   = f;  f += (size_t)N_NODES * 64;
    float* aS1  = f;  f += (size_t)N_NODES * 8;
    float* aD1  = f;  f += (size_t)N_NODES * 8;
    float* helu = f;  f += (size_t)N_NODES * 64;
    float* h2   = f;  f += (size_t)N_NODES * 40;
    float* a2s  = f;  f += (size_t)N_NODES;
    float* a2d  = f;  f += (size_t)N_NODES;
    float* ew1  = f;  f += (size_t)E * 8;       // layer-1 weights [E][8]
    float* ew2  = ew1;                          // layer-2 aliases layer-1
    short* bph = (short*)f;  f += 16384;        // 512*64 shorts (64 KB)
    short* bpl = (short*)f;  f += 16384;
    int2* pairs = (int2*)f;  f += (size_t)E * 2;
    int* ip = (int*)f;
    int* deg       = ip;  ip += N_NODES;
    int* scanned   = ip;  ip += N_NODES;
    int* cum       = ip;  ip += N_NODES;
    int* partials  = ip;  ip += 256;
    int* coarseCur = ip;  ip += NB;
    int* ssrc      = ip;  ip += E;

    const int nScanBlocks = (N_NODES + 255) / 256;   // 196
    const int eBlocks = (E + 255) / 256;
    const int partBlocks = (E + TILE - 1) / TILE;

    // ---- CSR build (same graph serves both layers)
    hipMemsetAsync(deg, 0, N_NODES * sizeof(int), stream);
    k_count<<<eBlocks, 256, 0, stream>>>(dst, E, deg);
    k_scan_block<<<nScanBlocks, 256, 0, stream>>>(deg, scanned, partials, N_NODES);
    k_scan_partials<<<1, 256, 0, stream>>>(partials, nScanBlocks);
    k_scan_add<<<nScanBlocks, 256, 0, stream>>>(scanned, partials, cum, coarseCur, N_NODES);
    k_part<<<partBlocks, 256, 0, stream>>>(src, dst, E, coarseCur, pairs);
    k_fine<<<NB, 256, 0, stream>>>(cum, pairs, ssrc);

    // ---- Layer 1
    k_packW<<<(512 * 64 + 255) / 256, 256, 0, stream>>>(W1, bph, bpl);
    k_gemm1_mfma<<<(N_NODES + 31) / 32, 256, 0, stream>>>(x, bph, bpl, attS1, attD1,
                                                          h1, aS1, aD1);
    k_wt1_node<<<N_NODES / 4, 256, 0, stream>>>(cum, ssrc, aS1, aD1, ew1);
    k_agg1<<<N_NODES / 4, 256, 0, stream>>>(cum, ssrc, ew1, aS1, aD1, h1, b1, helu);

    // ---- Layer 2
    k_gemm2<<<N_NODES / 4, 256, 0, stream>>>(helu, W2, attS2, attD2, h2, a2s, a2d);
    k_wt2_node<<<N_NODES / 4, 256, 0, stream>>>(cum, ssrc, a2s, a2d, ew2);
    k_agg2<<<N_NODES / 4, 256, 0, stream>>>(cum, ssrc, ew2, a2s, a2d, h2, b2, out);
}

// Round 6
// 295.620 us; speedup vs baseline: 18.7003x; 1.3033x over previous
//
#include <hip/hip_runtime.h>
#include <math.h>

#define N_NODES 50000
#define IN_CH   512
#define HID     8
#define HEADS   8
#define C1      64      // HEADS*HID
#define OUT_CH  40
#define NEG_SLOPE 0.2f
#define NB      ((N_NODES + 255) / 256)   // 196 coarse buckets (dst>>8)
#define TILE    4096                      // edges per k_part block

__device__ __forceinline__ float leaky(float v) { return v > 0.f ? v : NEG_SLOPE * v; }

typedef __attribute__((ext_vector_type(8))) short short8;
typedef __attribute__((ext_vector_type(4))) short short4v;
typedef __attribute__((ext_vector_type(4))) float f32x4;

__device__ __forceinline__ unsigned short f2bf(float f) {
    unsigned u = __builtin_bit_cast(unsigned, f);
    u += 0x7FFFu + ((u >> 16) & 1u);          // round-to-nearest-even
    return (unsigned short)(u >> 16);
}
__device__ __forceinline__ float bf2f(unsigned short h) {
    unsigned u = ((unsigned)h) << 16;
    return __builtin_bit_cast(float, u);
}

#define XH_STRIDE_B 272   // bytes per LDS row: 128 bf16 = 256B + 16 pad

// ---------------------------------------------------------------------------
// Pack W1 (512x64 fp32) into MFMA B-fragment order, bf16 hi/lo.
// ---------------------------------------------------------------------------
__global__ __launch_bounds__(256) void k_packW(
    const float* __restrict__ W1, short* __restrict__ bph, short* __restrict__ bpl)
{
    const int idx = blockIdx.x * 256 + threadIdx.x;
    if (idx >= 512 * 64) return;
    const int k = idx >> 6, col = idx & 63;
    const float w = W1[idx];
    const unsigned short hi = f2bf(w);
    const unsigned short lo = f2bf(w - bf2f(hi));
    const int di = ((k >> 5) * 64 + col) * 32 + (k & 31);
    bph[di] = (short)hi;
    bpl[di] = (short)lo;
}

// ---------------------------------------------------------------------------
// K1 (MFMA): h1 = (x @ W1) / rowsum(x), bf16x3 split, software-pipelined.
// block = 256 (4 waves); 32 rows x 64 cols; wave = 16 rows x 32 cols.
// ---------------------------------------------------------------------------
__global__ __launch_bounds__(256) void k_gemm1_mfma(
    const float* __restrict__ x,
    const short* __restrict__ bph, const short* __restrict__ bpl,
    const float* __restrict__ attS, const float* __restrict__ attD,
    float* __restrict__ h1, float* __restrict__ aS, float* __restrict__ aD)
{
    __shared__ unsigned char smem[17536];
    short* xh = (short*)smem;                      // [32] rows x 136 shorts
    short* xl = (short*)(smem + 8704);
    float* rowsum = (float*)(smem + 17408);        // [32]
    float* houtf  = (float*)smem;                  // [32][68] (aliases xh/xl)

    const int tid  = threadIdx.x;
    const int lane = tid & 63;
    const int w    = tid >> 6;
    const int row_off = (w & 1) * 16;
    const int col_off = (w >> 1) * 32;
    const int rowBase = blockIdx.x * 32;

    const int l15 = lane & 15;
    const int kg  = lane >> 4;
    const int a_base = (l15 + row_off) * XH_STRIDE_B + kg * 16;

    const int srow = tid >> 5;          // staging row-group 0..7
    const int sk4  = tid & 31;          // staging k4 slot

    f32x4 acc0 = {0.f, 0.f, 0.f, 0.f};
    f32x4 acc1 = {0.f, 0.f, 0.f, 0.f};
    float psum[4] = {0.f, 0.f, 0.f, 0.f};
    float4 va[4], vb[4];

    auto LOAD = [&](int c, float4 (&v)[4]) {
        #pragma unroll
        for (int i = 0; i < 4; ++i) {
            const int grow = rowBase + i * 8 + srow;
            v[i] = (grow < N_NODES)
                 ? *(const float4*)(x + (size_t)grow * IN_CH + c * 128 + sk4 * 4)
                 : make_float4(0.f, 0.f, 0.f, 0.f);
        }
    };
    auto STAGE = [&](float4 (&v)[4]) {
        #pragma unroll
        for (int i = 0; i < 4; ++i) {
            const int row = i * 8 + srow;
            const unsigned short h0 = f2bf(v[i].x), h1u = f2bf(v[i].y),
                                 h2 = f2bf(v[i].z), h3  = f2bf(v[i].w);
            short4v hvv = { (short)h0, (short)h1u, (short)h2, (short)h3 };
            short4v lvv = { (short)f2bf(v[i].x - bf2f(h0)), (short)f2bf(v[i].y - bf2f(h1u)),
                            (short)f2bf(v[i].z - bf2f(h2)), (short)f2bf(v[i].w - bf2f(h3)) };
            *(short4v*)((char*)xh + row * XH_STRIDE_B + sk4 * 8) = hvv;
            *(short4v*)((char*)xl + row * XH_STRIDE_B + sk4 * 8) = lvv;
            psum[i] += v[i].x + v[i].y + v[i].z + v[i].w;
        }
    };
    auto MFMA = [&](int c) {
        #pragma unroll
        for (int kk2 = 0; kk2 < 4; ++kk2) {
            const int kk = c * 4 + kk2;
            const short8 ah = *(const short8*)((const char*)xh + a_base + kk2 * 64);
            const short8 al = *(const short8*)((const char*)xl + a_base + kk2 * 64);
            const int b0 = (kk * 64 + col_off + l15) * 32 + kg * 8;
            const int b1 = b0 + 16 * 32;
            const short8 bh0 = *(const short8*)(bph + b0);
            const short8 bl0 = *(const short8*)(bpl + b0);
            const short8 bh1 = *(const short8*)(bph + b1);
            const short8 bl1 = *(const short8*)(bpl + b1);
            acc0 = __builtin_amdgcn_mfma_f32_16x16x32_bf16(ah, bh0, acc0, 0, 0, 0);
            acc1 = __builtin_amdgcn_mfma_f32_16x16x32_bf16(ah, bh1, acc1, 0, 0, 0);
            acc0 = __builtin_amdgcn_mfma_f32_16x16x32_bf16(ah, bl0, acc0, 0, 0, 0);
            acc1 = __builtin_amdgcn_mfma_f32_16x16x32_bf16(ah, bl1, acc1, 0, 0, 0);
            acc0 = __builtin_amdgcn_mfma_f32_16x16x32_bf16(al, bh0, acc0, 0, 0, 0);
            acc1 = __builtin_amdgcn_mfma_f32_16x16x32_bf16(al, bh1, acc1, 0, 0, 0);
        }
    };

    // pipelined: loads for chunk c+1 issued before MFMA of chunk c
    LOAD(0, va);
    STAGE(va);
    __syncthreads();
    LOAD(1, vb);
    MFMA(0);
    __syncthreads();
    STAGE(vb);
    __syncthreads();
    LOAD(2, va);
    MFMA(1);
    __syncthreads();
    STAGE(va);
    __syncthreads();
    LOAD(3, vb);
    MFMA(2);
    __syncthreads();
    STAGE(vb);
    // rowsum: register partials -> 32-lane butterfly -> one LDS store per row
    #pragma unroll
    for (int i = 0; i < 4; ++i) {
        float s = psum[i];
        #pragma unroll
        for (int off = 16; off; off >>= 1) s += __shfl_xor(s, off, 32);
        if (sk4 == 0) rowsum[i * 8 + srow] = s;
    }
    __syncthreads();
    MFMA(3);
    __syncthreads();

    // ---- epilogue: normalize, stash fp32 tile in LDS (aliases xh/xl)
    #pragma unroll
    for (int r = 0; r < 4; ++r) {
        const int row = row_off + kg * 4 + r;   // C/D: row=(lane>>4)*4+reg
        const float rs = fmaxf(rowsum[row], 1e-8f);
        houtf[row * 68 + col_off + l15]      = acc0[r] / rs;
        houtf[row * 68 + col_off + 16 + l15] = acc1[r] / rs;
    }
    __syncthreads();

    // coalesced h1 write
    #pragma unroll
    for (int i = tid; i < 32 * 16; i += 256) {
        const int row = i >> 4, seg = i & 15;
        if (rowBase + row < N_NODES)
            *(float4*)(h1 + (size_t)(rowBase + row) * 64 + seg * 4) =
                *(const float4*)(houtf + row * 68 + seg * 4);
    }

    // logits: thread = (row, head)
    {
        const int row = tid >> 3, hd = tid & 7;
        if (rowBase + row < N_NODES) {
            float vs = 0.f, vd = 0.f;
            #pragma unroll
            for (int e2 = 0; e2 < 8; ++e2) {
                const float hv = houtf[row * 68 + hd * 8 + e2];
                vs = fmaf(hv, attS[hd * 8 + e2], vs);
                vd = fmaf(hv, attD[hd * 8 + e2], vd);
            }
            aS[(size_t)(rowBase + row) * 8 + hd] = vs;
            aD[(size_t)(rowBase + row) * 8 + hd] = vd;
        }
    }
}

// ---------------------------------------------------------------------------
// CSR build pass 0: coarse histogram (196 buckets) via LDS, few global atomics
// ---------------------------------------------------------------------------
__global__ __launch_bounds__(256) void k_chist(
    const int* __restrict__ dst, int E, int* __restrict__ gcount)
{
    __shared__ int hist[256];
    const int t = threadIdx.x;
    const int tileBase = blockIdx.x * TILE;
    const int n = min(TILE, E - tileBase);
    hist[t] = 0;
    __syncthreads();
    for (int e = t; e < n; e += 256)
        atomicAdd(&hist[dst[tileBase + e] >> 8], 1);
    __syncthreads();
    if (t < NB && hist[t]) atomicAdd(&gcount[t], hist[t]);
}

// scan 196 coarse counts -> exclusive bases + scatter cursors (1 block)
__global__ __launch_bounds__(256) void k_cscan(
    const int* __restrict__ gcount, int* __restrict__ cbaseX,
    int* __restrict__ coarseCur)
{
    __shared__ int tmp[256];
    const int t = threadIdx.x;
    tmp[t] = (t < NB) ? gcount[t] : 0;
    __syncthreads();
    #pragma unroll
    for (int off = 1; off < 256; off <<= 1) {
        int xv = (t >= off) ? tmp[t - off] : 0;
        __syncthreads();
        tmp[t] += xv;
        __syncthreads();
    }
    if (t < NB) {
        const int ex = tmp[t] - gcount[t];
        cbaseX[t] = ex;
        coarseCur[t] = ex;
    }
}

// ---------------------------------------------------------------------------
// Pass A: coarse partition of (src,dst) pairs by dst>>8 with LDS reorder
// ---------------------------------------------------------------------------
__global__ __launch_bounds__(256) void k_part(
    const int* __restrict__ src, const int* __restrict__ dst, int E,
    int* __restrict__ coarseCur, int2* __restrict__ pairs)
{
    __shared__ int  hist[256];
    __shared__ int  scn[256];
    __shared__ int  offs[256];
    __shared__ int2 pairBuf[TILE];

    const int t = threadIdx.x;
    const int tileBase = blockIdx.x * TILE;
    const int n = min(TILE, E - tileBase);

    hist[t] = 0;
    __syncthreads();

    for (int e = t; e < n; e += 256)
        atomicAdd(&hist[dst[tileBase + e] >> 8], 1);
    __syncthreads();

    scn[t] = hist[t];
    __syncthreads();
    #pragma unroll
    for (int off = 1; off < 256; off <<= 1) {
        int xv = (t >= off) ? scn[t - off] : 0;
        __syncthreads();
        scn[t] += xv;
        __syncthreads();
    }

    {
        const int h  = hist[t];
        const int ls = scn[t] - h;
        int off = 0;
        if (h > 0) {
            const int gbase = atomicAdd(&coarseCur[t], h);
            off = gbase - ls;
        }
        offs[t] = off;
        hist[t] = ls;
    }
    __syncthreads();

    for (int e = t; e < n; e += 256) {
        const int s = src[tileBase + e];
        const int d = dst[tileBase + e];
        const int pos = atomicAdd(&hist[d >> 8], 1);
        pairBuf[pos] = make_int2(s, d);
    }
    __syncthreads();

    for (int i = t; i < n; i += 256) {
        const int2 p = pairBuf[i];
        pairs[i + offs[p.y >> 8]] = p;
    }
}

// ---------------------------------------------------------------------------
// Pass B: per coarse bucket: fine histogram -> scan -> cum write -> scatter.
// ---------------------------------------------------------------------------
__global__ __launch_bounds__(256) void k_fine2(
    const int* __restrict__ cbaseX, const int* __restrict__ gcount,
    const int2* __restrict__ pairs, int* __restrict__ ssrc,
    int* __restrict__ cum)
{
    __shared__ int hist[256];
    __shared__ int scn[256];
    __shared__ int cur[256];
    const int b = blockIdx.x;
    const int t = threadIdx.x;
    const int dbase = b << 8;
    const int nd = min(256, N_NODES - dbase);
    const int lo = cbaseX[b];
    const int hi = lo + gcount[b];

    hist[t] = 0;
    __syncthreads();
    for (int j = lo + t; j < hi; j += 256)
        atomicAdd(&hist[pairs[j].y - dbase], 1);
    __syncthreads();

    const int hv = hist[t];
    scn[t] = hv;
    __syncthreads();
    #pragma unroll
    for (int off = 1; off < 256; off <<= 1) {
        int xv = (t >= off) ? scn[t - off] : 0;
        __syncthreads();
        scn[t] += xv;
        __syncthreads();
    }
    if (t < nd) cum[dbase + t] = lo + scn[t];
    cur[t] = lo + scn[t] - hv;
    __syncthreads();

    for (int j = lo + t; j < hi; j += 256) {
        const int2 p = pairs[j];
        const int pos = atomicAdd(&cur[p.y - dbase], 1);
        ssrc[pos] = p.x;
    }
}

// ---------------------------------------------------------------------------
// Edge weights layer 1, CSR slot order; wave per node (dst uniform).
// ---------------------------------------------------------------------------
__global__ __launch_bounds__(256) void k_wt1_node(
    const int* __restrict__ cum, const int* __restrict__ ssrc,
    const float* __restrict__ aS, const float* __restrict__ aD,
    float* __restrict__ ew)
{
    const int lane = threadIdx.x & 63;
    const int node = __builtin_amdgcn_readfirstlane(blockIdx.x * 4 + (threadIdx.x >> 6));
    const int start = node ? cum[node - 1] : 0;
    const int end   = cum[node];
    const int h = lane & 7;
    const float aDn = aD[(size_t)node * 8 + h];

    for (int k0 = start; k0 < end; k0 += 8) {
        const int slot = k0 + (lane >> 3);
        if (slot < end) {
            const int s = ssrc[slot];
            ew[(size_t)slot * 8 + h] = expf(leaky(aS[(size_t)s * 8 + h] + aDn));
        }
    }
}

__global__ __launch_bounds__(256) void k_wt2_node(
    const int* __restrict__ cum, const int* __restrict__ ssrc,
    const float* __restrict__ a2s, const float* __restrict__ a2d,
    float* __restrict__ ew)
{
    const int lane = threadIdx.x & 63;
    const int node = __builtin_amdgcn_readfirstlane(blockIdx.x * 4 + (threadIdx.x >> 6));
    const int start = node ? cum[node - 1] : 0;
    const int end   = cum[node];
    const float aDn = a2d[node];

    for (int k = start + lane; k < end; k += 64) {
        const int s = ssrc[k];
        ew[k] = expf(leaky(a2s[s] + aDn));
    }
}

// ---------------------------------------------------------------------------
// K-AGG1: one wave per dst node; lane = channel; wave-uniform scalar edge walk.
// ---------------------------------------------------------------------------
__global__ __launch_bounds__(256) void k_agg1(
    const int* __restrict__ cum, const int* __restrict__ ssrc,
    const float* __restrict__ ew,
    const float* __restrict__ aS, const float* __restrict__ aD,
    const float* __restrict__ h1, const float* __restrict__ b1,
    float* __restrict__ helu)
{
    const int lane = threadIdx.x & 63;
    const int node = __builtin_amdgcn_readfirstlane(blockIdx.x * 4 + (threadIdx.x >> 6));
    const int h = lane >> 3;

    const int start = node ? cum[node - 1] : 0;
    const int end   = cum[node];

    const float e0 = expf(leaky(aS[(size_t)node * 8 + h] + aD[(size_t)node * 8 + h]));
    float acc = e0 * h1[(size_t)node * 64 + lane];
    float den = e0;

    #pragma unroll 4
    for (int k = start; k < end; ++k) {
        const int s   = ssrc[k];
        const float w = ew[(size_t)k * 8 + h];
        acc = fmaf(w, h1[(size_t)s * 64 + lane], acc);
        den += w;
    }

    const float v = acc / (den + 1e-16f) + b1[lane];
    helu[(size_t)node * 64 + lane] = v > 0.f ? v : expm1f(v);
}

// ---------------------------------------------------------------------------
// K4: h2 = helu @ W2 (64x40); layer-2 logits a2s/a2d.
// ---------------------------------------------------------------------------
__global__ __launch_bounds__(256) void k_gemm2(
    const float* __restrict__ helu, const float* __restrict__ W2,
    const float* __restrict__ attS2, const float* __restrict__ attD2,
    float* __restrict__ h2, float* __restrict__ a2s, float* __restrict__ a2d)
{
    __shared__ float w2s[64 * 40];
    __shared__ float xs[4][64];
    const int tid = threadIdx.x;
    for (int i = tid; i < 64 * 40; i += 256) w2s[i] = W2[i];
    const int rowBase = blockIdx.x * 4;
    xs[tid >> 6][tid & 63] = helu[(size_t)rowBase * 64 + tid];
    __syncthreads();

    const int w = tid >> 6;
    const int j = tid & 63;
    const int row = rowBase + w;

    float acc = 0.f;
    if (j < OUT_CH) {
        #pragma unroll
        for (int k = 0; k < 64; ++k)
            acc = fmaf(xs[w][k], w2s[k * 40 + j], acc);
    }
    float vs = (j < OUT_CH) ? acc * attS2[j] : 0.f;
    float vd = (j < OUT_CH) ? acc * attD2[j] : 0.f;
    #pragma unroll
    for (int off = 32; off; off >>= 1) {
        vs += __shfl_xor(vs, off, 64);
        vd += __shfl_xor(vd, off, 64);
    }
    if (j < OUT_CH) h2[(size_t)row * 40 + j] = acc;
    if (j == 0) {
        a2s[row] = vs;
        a2d[row] = vd;
    }
}

// ---------------------------------------------------------------------------
// K-AGG2: one wave per dst node, lanes 0..39 = channels; scalar edge walk.
// ---------------------------------------------------------------------------
__global__ __launch_bounds__(256) void k_agg2(
    const int* __restrict__ cum, const int* __restrict__ ssrc,
    const float* __restrict__ ew,
    const float* __restrict__ a2s, const float* __restrict__ a2d,
    const float* __restrict__ h2, const float* __restrict__ b2,
    float* __restrict__ out)
{
    const int lane = threadIdx.x & 63;
    const int node = __builtin_amdgcn_readfirstlane(blockIdx.x * 4 + (threadIdx.x >> 6));

    const int start = node ? cum[node - 1] : 0;
    const int end   = cum[node];

    const float e0 = expf(leaky(a2s[node] + a2d[node]));
    float acc = (lane < OUT_CH) ? e0 * h2[(size_t)node * 40 + lane] : 0.f;
    float den = e0;

    #pragma unroll 4
    for (int k = start; k < end; ++k) {
        const int s   = ssrc[k];
        const float w = ew[k];
        const float hv = (lane < OUT_CH) ? h2[(size_t)s * 40 + lane] : 0.f;
        acc = fmaf(w, hv, acc);
        den += w;
    }

    if (lane < OUT_CH)
        out[(size_t)node * OUT_CH + lane] = acc / (den + 1e-16f) + b2[lane];
}

// ---------------------------------------------------------------------------
extern "C" void kernel_launch(void* const* d_in, const int* in_sizes, int n_in,
                              void* d_out, int out_size, void* d_ws, size_t ws_size,
                              hipStream_t stream)
{
    const float* x     = (const float*)d_in[0];
    const int*   ei    = (const int*)d_in[1];
    const float* W1    = (const float*)d_in[2];
    const float* attS1 = (const float*)d_in[3];
    const float* attD1 = (const float*)d_in[4];
    const float* b1    = (const float*)d_in[5];
    const float* W2    = (const float*)d_in[6];
    const float* attS2 = (const float*)d_in[7];
    const float* attD2 = (const float*)d_in[8];
    const float* b2    = (const float*)d_in[9];

    const int E = in_sizes[1] / 2;
    const int* src = ei;
    const int* dst = ei + E;

    float* out = (float*)d_out;
    float* f = (float*)d_ws;
    float* h1   = f;  f += (size_t)N_NODES * 64;
    float* aS1  = f;  f += (size_t)N_NODES * 8;
    float* aD1  = f;  f += (size_t)N_NODES * 8;
    float* helu = f;  f += (size_t)N_NODES * 64;
    float* h2   = f;  f += (size_t)N_NODES * 40;
    float* a2s  = f;  f += (size_t)N_NODES;
    float* a2d  = f;  f += (size_t)N_NODES;
    float* ew1  = f;  f += (size_t)E * 8;       // layer-1 weights [E][8]
    float* ew2  = ew1;                          // layer-2 aliases layer-1
    short* bph = (short*)f;  f += 16384;        // 512*64 shorts (64 KB)
    short* bpl = (short*)f;  f += 16384;
    int2* pairs = (int2*)f;  f += (size_t)E * 2;
    int* ip = (int*)f;
    int* gcount    = ip;  ip += 256;
    int* cbaseX    = ip;  ip += 256;
    int* coarseCur = ip;  ip += 256;
    int* cum       = ip;  ip += N_NODES;
    int* ssrc      = ip;  ip += E;

    const int partBlocks = (E + TILE - 1) / TILE;

    // ---- CSR build (no 50K-array global atomics anywhere)
    hipMemsetAsync(gcount, 0, 256 * sizeof(int), stream);
    k_chist<<<partBlocks, 256, 0, stream>>>(dst, E, gcount);
    k_cscan<<<1, 256, 0, stream>>>(gcount, cbaseX, coarseCur);
    k_part<<<partBlocks, 256, 0, stream>>>(src, dst, E, coarseCur, pairs);
    k_fine2<<<NB, 256, 0, stream>>>(cbaseX, gcount, pairs, ssrc, cum);

    // ---- Layer 1
    k_packW<<<(512 * 64 + 255) / 256, 256, 0, stream>>>(W1, bph, bpl);
    k_gemm1_mfma<<<(N_NODES + 31) / 32, 256, 0, stream>>>(x, bph, bpl, attS1, attD1,
                                                          h1, aS1, aD1);
    k_wt1_node<<<N_NODES / 4, 256, 0, stream>>>(cum, ssrc, aS1, aD1, ew1);
    k_agg1<<<N_NODES / 4, 256, 0, stream>>>(cum, ssrc, ew1, aS1, aD1, h1, b1, helu);

    // ---- Layer 2
    k_gemm2<<<N_NODES / 4, 256, 0, stream>>>(helu, W2, attS2, attD2, h2, a2s, a2d);
    k_wt2_node<<<N_NODES / 4, 256, 0, stream>>>(cum, ssrc, a2s, a2d, ew2);
    k_agg2<<<N_NODES / 4, 256, 0, stream>>>(cum, ssrc, ew2, a2s, a2d, h2, b2, out);
}